// Round 1
// 572.863 us; speedup vs baseline: 1.1770x; 1.1770x over previous
//
#include <hip/hip_runtime.h>

typedef __bf16 bf16;
typedef _Float16 f16;
typedef bf16 bf16x8 __attribute__((ext_vector_type(8)));
typedef bf16 bf16x4 __attribute__((ext_vector_type(4)));
typedef f16 f16x4 __attribute__((ext_vector_type(4)));
typedef float f32x4 __attribute__((ext_vector_type(4)));

// B=2, L=1024, D=1024, H=16, HD=64, FFN=2048, TEMP=8, EPS=1e-5. All I/O f32.

// ---------------------------------------------------------------- prep: 7 transposes + x cast, one kernel
// blocks 0..5119   : wq/wk/wv/wg/wo transpose (1024x1024), 1024 tiles each
// blocks 5120..7167: w1 transpose (1024x2048 -> 2048x1024), 2048 tiles
// blocks 7168..9215: w2 transpose (2048x1024 -> 1024x2048), 2048 tiles
// blocks 9216..11263: x f32 -> bf16 cast (2M elements)
__global__ __launch_bounds__(256) void kprep(
    const float* __restrict__ x, bf16* __restrict__ xbf,
    const float* __restrict__ wq, const float* __restrict__ wk, const float* __restrict__ wv,
    const float* __restrict__ wg, const float* __restrict__ wo, const float* __restrict__ w1,
    const float* __restrict__ w2, bf16* __restrict__ wqT, bf16* __restrict__ wkT,
    bf16* __restrict__ wvT, bf16* __restrict__ wgT, bf16* __restrict__ woT,
    bf16* __restrict__ w1T, bf16* __restrict__ w2T) {
  int bid = blockIdx.x;
  int tid = threadIdx.x;

  if (bid >= 9216) {  // cast segment
    int i = (bid - 9216) * 256 + tid;
    f32x4 v = *(const f32x4*)(x + (long)i * 4);
    bf16x4 o;
#pragma unroll
    for (int j = 0; j < 4; j++) o[j] = (bf16)v[j];
    *(bf16x4*)(xbf + (long)i * 4) = o;
    return;
  }

  __shared__ float t[32][33];
  const float* src;
  bf16* dst;
  int R, C, tile;
  if (bid < 5120) {
    int seg = bid >> 10;
    tile = bid & 1023;
    R = 1024; C = 1024;
    if (seg == 0) { src = wq; dst = wqT; }
    else if (seg == 1) { src = wk; dst = wkT; }
    else if (seg == 2) { src = wv; dst = wvT; }
    else if (seg == 3) { src = wg; dst = wgT; }
    else { src = wo; dst = woT; }
  } else if (bid < 7168) {
    tile = bid - 5120; R = 1024; C = 2048; src = w1; dst = w1T;
  } else {
    tile = bid - 7168; R = 2048; C = 1024; src = w2; dst = w2T;
  }
  int txs = (C == 2048) ? 6 : 5;  // tiles along C
  int c0 = (tile & ((1 << txs) - 1)) << 5, r0 = (tile >> txs) << 5;
  int tx = tid & 31, ty = tid >> 5;
#pragma unroll
  for (int i = 0; i < 32; i += 8)
    t[ty + i][tx] = src[(long)(r0 + ty + i) * C + c0 + tx];
  __syncthreads();
#pragma unroll
  for (int i = 0; i < 32; i += 8)
    dst[(long)(c0 + ty + i) * R + r0 + tx] = (bf16)t[tx][ty + i];
}

// ---------------------------------------------------------------- GEMM (C = A * Bt^T), MFMA bf16
static constexpr int MODE_QK = 0;        // out bf16 [b,h,l,hd], alpha scale
static constexpr int MODE_VT = 1;        // out bf16 [b,h,hd,l]
static constexpr int MODE_G = 2;         // out f32 = sigmoid(acc + bias[n])
static constexpr int MODE_SCOREF16 = 3;  // out f16 [b,h,q,k] contiguous (z = b*16+h)
static constexpr int MODE_SCORE_SC = 4;  // out f32 scattered [b,q,k,h] (fallback)
static constexpr int MODE_PV = 5;        // A=Pws bf16 [b,h,q,k]; out bf16 gated
static constexpr int MODE_PV_SLOW = 6;   // A=attn f32 [b,q,k,h] strided; out bf16 gated
static constexpr int MODE_WO = 7;        // out f32 = acc + bias[n]
static constexpr int MODE_FFN1 = 8;      // out bf16 = silu(acc + bias[n])
static constexpr int MODE_FFN2 = 9;      // out f32 = acc + bias[n]
static constexpr int MODE_QKVG = 10;     // fused Q|K|V|G projections, N=4096; Out=qws base

template <int MODE>
__global__ __launch_bounds__(256) void gemm_bt(
    const void* __restrict__ Av, const bf16* __restrict__ Bt, void* __restrict__ Out,
    const float* __restrict__ bias, const float* __restrict__ gate,
    int M, int N, int K, int lda, int ldb, long sA, long sB, float alpha) {
  const int z = blockIdx.z;
  const bf16* A = (const bf16*)Av + (long)z * sA;
  Bt += (long)z * sB;
  const int bb = z >> 4, hh = z & 15;

  __shared__ bf16 As[128][40];  // 80B row stride -> 2-way (free) on ds_read_b128
  __shared__ bf16 Bs[128][40];

  const int tid = threadIdx.x;
  const int m0 = blockIdx.y * 128, n0 = blockIdx.x * 128;
  const int lane = tid & 63, wave = tid >> 6;
  const int wm = (wave >> 1) * 64, wn = (wave & 1) * 64;
  const int l15 = lane & 15, quad = lane >> 4;

  f32x4 acc[4][4] = {};

  for (int k0 = 0; k0 < K; k0 += 32) {
    bf16x8 av[2], bv[2];
#pragma unroll
    for (int u = 0; u < 2; u++) {
      int c = tid + u * 256;
      int row = c >> 2, kc = (c & 3) << 3;
      if (MODE == MODE_PV_SLOW) {
        const float* Af = (const float*)Av;
        long rb = ((long)bb << 24) + hh + ((long)(m0 + row) << 14) + ((long)(k0 + kc) << 4);
#pragma unroll
        for (int j = 0; j < 8; j++) av[u][j] = (bf16)Af[rb + j * 16];
      } else {
        av[u] = *(const bf16x8*)(A + (long)(m0 + row) * lda + (k0 + kc));
      }
      int brow = n0 + row;
      if (brow < N) {
        bv[u] = *(const bf16x8*)(Bt + (long)brow * ldb + (k0 + kc));
      } else {
#pragma unroll
        for (int j = 0; j < 8; j++) bv[u][j] = (bf16)0.0f;
      }
    }
    __syncthreads();
#pragma unroll
    for (int u = 0; u < 2; u++) {
      int c = tid + u * 256;
      int row = c >> 2, kc = (c & 3) << 3;
      *(bf16x8*)&As[row][kc] = av[u];
      *(bf16x8*)&Bs[row][kc] = bv[u];
    }
    __syncthreads();

    bf16x8 af[4], bfr[4];
#pragma unroll
    for (int t = 0; t < 4; t++) {
      af[t] = *(const bf16x8*)&As[wm + t * 16 + l15][quad << 3];
      bfr[t] = *(const bf16x8*)&Bs[wn + t * 16 + l15][quad << 3];
    }
#pragma unroll
    for (int mt = 0; mt < 4; mt++)
#pragma unroll
      for (int nt = 0; nt < 4; nt++)
        acc[mt][nt] =
            __builtin_amdgcn_mfma_f32_16x16x32_bf16(af[mt], bfr[nt], acc[mt][nt], 0, 0, 0);
  }

  // C/D layout: col=lane&15, row=quad*4+reg
#pragma unroll
  for (int mt = 0; mt < 4; mt++) {
#pragma unroll
    for (int nt = 0; nt < 4; nt++) {
#pragma unroll
      for (int r = 0; r < 4; r++) {
        int m = m0 + wm + mt * 16 + (quad << 2) + r;
        int n = n0 + wn + nt * 16 + l15;
        if (n >= N) continue;  // only PV (N=64)
        float v = acc[mt][nt][r] * alpha;
        if (MODE == MODE_QK) {
          long off = ((long)((m >> 10) * 16 + (n >> 6)) * 1024 + (m & 1023)) * 64 + (n & 63);
          ((bf16*)Out)[off] = (bf16)v;
        } else if (MODE == MODE_VT) {
          long off = ((long)((m >> 10) * 16 + (n >> 6)) * 64 + (n & 63)) * 1024 + (m & 1023);
          ((bf16*)Out)[off] = (bf16)v;
        } else if (MODE == MODE_G) {
          float t = v + bias[n];
          ((float*)Out)[(long)m * N + n] = 1.0f / (1.0f + __expf(-t));
        } else if (MODE == MODE_QKVG) {
          int sec = n >> 10, nn = n & 1023;
          bf16* ob = (bf16*)Out;  // qws base; kws/vtws/gws contiguous after it
          if (sec == 0) {
            long off = ((long)((m >> 10) * 16 + (nn >> 6)) * 1024 + (m & 1023)) * 64 + (nn & 63);
            ob[off] = (bf16)(v * 0.125f);
          } else if (sec == 1) {
            long off = ((long)((m >> 10) * 16 + (nn >> 6)) * 1024 + (m & 1023)) * 64 + (nn & 63);
            (ob + 2097152)[off] = (bf16)v;
          } else if (sec == 2) {
            long off = ((long)((m >> 10) * 16 + (nn >> 6)) * 64 + (nn & 63)) * 1024 + (m & 1023);
            (ob + 4194304)[off] = (bf16)v;
          } else {
            float t = v + bias[nn];
            ((float*)(ob + 6291456))[(long)m * 1024 + nn] = 1.0f / (1.0f + __expf(-t));
          }
        } else if (MODE == MODE_SCOREF16) {
          ((f16*)Out)[((long)z << 20) + ((long)m << 10) + n] = (f16)v;
        } else if (MODE == MODE_SCORE_SC) {
          long off = ((long)bb << 24) + ((long)m << 14) + ((long)n << 4) + hh;
          ((float*)Out)[off] = v;
        } else if (MODE == MODE_PV || MODE == MODE_PV_SLOW) {
          long off = ((long)(bb * 1024 + m)) * 1024 + hh * 64 + n;
          ((bf16*)Out)[off] = (bf16)(v * gate[off]);
        } else if (MODE == MODE_WO) {
          ((float*)Out)[(long)m * N + n] = v + bias[n];
        } else if (MODE == MODE_FFN1) {
          float t = v + bias[n];
          ((bf16*)Out)[(long)m * N + n] = (bf16)(t / (1.0f + __expf(-t)));
        } else {  // MODE_FFN2
          ((float*)Out)[(long)m * N + n] = v + bias[n];
        }
      }
    }
  }
}

// ---------------------------------------------------------------- bias + softmax, ALL 16 heads per (b,q)
// Scores f16 [b,h,q,k] in Sf; probs written bf16 IN PLACE (same bytes) + attn f32 [b,q,k,h].
// One block per (b,q): full 64B-line coalescing on ebias reads and attnf writes.
__global__ __launch_bounds__(256) void attn_softmax16(float* __restrict__ attnf,
                                                      void* __restrict__ Sf,
                                                      const float* __restrict__ ebias,
                                                      const unsigned char* __restrict__ mask) {
  __shared__ float sm[16][1028];
  __shared__ float invs[16];
  int bx = blockIdx.x;
  int q = bx & 1023, b = bx >> 10;
  int tid = threadIdx.x;
  int lane = tid & 63, wave = tid >> 6;
  long sbase = ((long)b << 24) + ((long)q << 14);  // [b,q,k,h] slice base

  // scores f16 [b,h,q,k] -> LDS f32 (row-contiguous b128 stores, conflict-free)
  const f16* S = (const f16*)Sf;
#pragma unroll
  for (int h = 0; h < 16; h++) {
    long rb = (((long)((b << 4) + h) << 10) + q) << 10;
    f16x4 v = *(const f16x4*)(S + rb + tid * 4);
    f32x4 f;
#pragma unroll
    for (int j = 0; j < 4; j++) f[j] = (float)v[j];
    *(f32x4*)&sm[h][tid * 4] = f;
  }
  __syncthreads();

  // + edge_bias [b,q,k,h]: fully coalesced f32x4 stream; LDS scatter is 2-way (free)
#pragma unroll
  for (int it = 0; it < 16; it++) {
    int j = tid + it * 256;
    int k = j >> 2, c = (j & 3) << 2;
    f32x4 e = *(const f32x4*)(ebias + sbase + ((long)k << 4) + c);
#pragma unroll
    for (int jj = 0; jj < 4; jj++) sm[c + jj][k] += e[jj];
  }
  __syncthreads();

  for (int k = tid; k < 1024; k += 256) {
    if (mask[(b << 10) + k]) {
#pragma unroll
      for (int h = 0; h < 16; h++) sm[h][k] = -1e30f;
    }
  }
  __syncthreads();

  // softmax over k, 4 heads per wave; leave unnormalized p in LDS, inv applied at output
  for (int h = wave * 4; h < wave * 4 + 4; h++) {
    float mx = -1e30f;
    for (int k = lane; k < 1024; k += 64) mx = fmaxf(mx, sm[h][k]);
#pragma unroll
    for (int d = 32; d; d >>= 1) mx = fmaxf(mx, __shfl_xor(mx, d, 64));
    float sum = 0.f;
    for (int k = lane; k < 1024; k += 64) {
      float p = __expf(sm[h][k] - mx);
      sm[h][k] = p;
      sum += p;
    }
#pragma unroll
    for (int d = 32; d; d >>= 1) sum += __shfl_xor(sum, d, 64);
    if (lane == 0) invs[h] = 1.0f / sum;
  }
  __syncthreads();

  // attn_out probs f32 [b,q,k,h]: fully coalesced f32x4 stream
#pragma unroll
  for (int it = 0; it < 16; it++) {
    int j = tid + it * 256;
    int k = j >> 2, c = (j & 3) << 2;
    f32x4 v;
#pragma unroll
    for (int jj = 0; jj < 4; jj++) v[jj] = sm[c + jj][k] * invs[c + jj];
    *(f32x4*)(attnf + sbase + ((long)k << 4) + c) = v;
  }
  // P bf16 [b,h,q,k], in place over the f16 scores (same slice, post-barrier safe)
#pragma unroll
  for (int h = 0; h < 16; h++) {
    long rb = (((long)((b << 4) + h) << 10) + q) << 10;
    float inv = invs[h];
    f32x4 f = *(const f32x4*)&sm[h][tid * 4];
    bf16x4 o;
#pragma unroll
    for (int j = 0; j < 4; j++) o[j] = (bf16)(f[j] * inv);
    *(bf16x4*)((bf16*)Sf + rb + tid * 4) = o;
  }
}

// ---------------------------------------------------------------- bias + softmax (fallback, f32 scattered)
template <int FAST>
__global__ __launch_bounds__(256) void attn_softmax(float* __restrict__ attnf,
                                                    void* __restrict__ Sf,
                                                    const float* __restrict__ ebias,
                                                    const unsigned char* __restrict__ mask) {
  __shared__ float sm[8][1028];
  int bx = blockIdx.x;
  int hb = (bx & 1) * 8;
  int q = (bx >> 1) & 1023;
  int b = bx >> 11;
  int tid = threadIdx.x;
  int lane = tid & 63, wave = tid >> 6;
  long sbase = ((long)b << 24) + ((long)q << 14) + hb;  // [b,q,k,h] slice base

  for (int i = tid; i < 2048; i += 256) {
    int k = i >> 1, c = (i & 1) * 4;
    long off = sbase + ((long)k << 4) + c;
    f32x4 s = *(const f32x4*)(attnf + off);
    f32x4 e = *(const f32x4*)(ebias + off);
#pragma unroll
    for (int j = 0; j < 4; j++) sm[c + j][k] = s[j] + e[j];
  }
  __syncthreads();

  for (int k = tid; k < 1024; k += 256) {
    if (mask[(b << 10) + k]) {
#pragma unroll
      for (int h = 0; h < 8; h++) sm[h][k] = -1e30f;
    }
  }
  __syncthreads();

  for (int h = wave * 2; h < wave * 2 + 2; h++) {
    float mx = -1e30f;
    for (int k = lane; k < 1024; k += 64) mx = fmaxf(mx, sm[h][k]);
#pragma unroll
    for (int d = 32; d; d >>= 1) mx = fmaxf(mx, __shfl_xor(mx, d, 64));
    float sum = 0.f;
    for (int k = lane; k < 1024; k += 64) {
      float p = __expf(sm[h][k] - mx);
      sm[h][k] = p;
      sum += p;
    }
#pragma unroll
    for (int d = 32; d; d >>= 1) sum += __shfl_xor(sum, d, 64);
    float inv = 1.0f / sum;
    for (int k = lane; k < 1024; k += 64) sm[h][k] *= inv;
  }
  __syncthreads();

  for (int i = tid; i < 2048; i += 256) {
    int k = i >> 1, c = (i & 1) * 4;
    f32x4 v;
#pragma unroll
    for (int j = 0; j < 4; j++) v[j] = sm[c + j][k];
    *(f32x4*)(attnf + sbase + ((long)k << 4) + c) = v;
  }
}

// ---------------------------------------------------------------- layernorm (1024 cols)
template <int MODE>
__global__ __launch_bounds__(256) void layernorm_k(
    const float* __restrict__ a32, const float* __restrict__ b32, const float* __restrict__ g,
    const float* __restrict__ be, float* __restrict__ of32, bf16* __restrict__ obf) {
  __shared__ float red[8];
  long base = (long)blockIdx.x << 10;
  int tid = threadIdx.x;
  int lane = tid & 63, wave = tid >> 6;
  float h[4], sum = 0.f, sq = 0.f;
#pragma unroll
  for (int t = 0; t < 4; t++) {
    int i = tid + t * 256;
    float v = a32[base + i] + b32[base + i];
    h[t] = v;
    sum += v;
    sq += v * v;
  }
#pragma unroll
  for (int d = 32; d; d >>= 1) {
    sum += __shfl_xor(sum, d, 64);
    sq += __shfl_xor(sq, d, 64);
  }
  if (lane == 0) { red[wave] = sum; red[4 + wave] = sq; }
  __syncthreads();
  sum = red[0] + red[1] + red[2] + red[3];
  sq = red[4] + red[5] + red[6] + red[7];
  float mean = sum * (1.0f / 1024.0f);
  float var = sq * (1.0f / 1024.0f) - mean * mean;
  float rstd = rsqrtf(var + 1e-5f);
#pragma unroll
  for (int t = 0; t < 4; t++) {
    int i = tid + t * 256;
    float o = (h[t] - mean) * rstd * g[i] + be[i];
    of32[base + i] = o;
    if (MODE == 0) obf[base + i] = (bf16)o;
  }
}

// ---------------------------------------------------------------- launch
extern "C" void kernel_launch(void* const* d_in, const int* in_sizes, int n_in, void* d_out,
                              int out_size, void* d_ws, size_t ws_size, hipStream_t stream) {
  const float* x = (const float*)d_in[0];
  const float* ebias = (const float*)d_in[1];
  const unsigned char* pmask = (const unsigned char*)d_in[2];
  const float* wq = (const float*)d_in[3];
  const float* wk = (const float*)d_in[4];
  const float* wv = (const float*)d_in[5];
  const float* wo = (const float*)d_in[6];
  const float* bo = (const float*)d_in[7];
  const float* wg = (const float*)d_in[8];
  const float* bg = (const float*)d_in[9];
  const float* w1 = (const float*)d_in[10];
  const float* b1 = (const float*)d_in[11];
  const float* w2 = (const float*)d_in[12];
  const float* b2 = (const float*)d_in[13];
  const float* ln1g = (const float*)d_in[14];
  const float* ln1b = (const float*)d_in[15];
  const float* ln2g = (const float*)d_in[16];
  const float* ln2b = (const float*)d_in[17];

  char* p = (char*)d_ws;
  bf16* xbf = (bf16*)p;  p += 4194304;
  bf16* wqT = (bf16*)p;  p += 2097152;   // wqT/wkT/wvT/wgT contiguous -> one [4096][1024] B matrix
  bf16* wkT = (bf16*)p;  p += 2097152;
  bf16* wvT = (bf16*)p;  p += 2097152;
  bf16* wgT = (bf16*)p;  p += 2097152;
  bf16* woT = (bf16*)p;  p += 2097152;
  bf16* w1T = (bf16*)p;  p += 4194304;
  bf16* w2T = (bf16*)p;  p += 4194304;
  bf16* qws = (bf16*)p;  p += 4194304;    // [b,h,l,hd]   (QKVG epilogue writes kws/vtws/gws via offsets)
  bf16* kws = (bf16*)p;  p += 4194304;    // [b,h,l,hd]
  bf16* vtws = (bf16*)p; p += 4194304;    // [b,h,hd,l]
  float* gws = (float*)p; p += 8388608;   // sigmoid gate f32
  bf16* ows = (bf16*)p;  p += 4194304;
  float* delta = (float*)p; p += 8388608;
  bf16* x1bf = (bf16*)p; p += 4194304;
  float* x1f = (float*)p; p += 8388608;
  bf16* ffn1 = (bf16*)p; p += 8388608;
  float* ffn2 = (float*)p; p += 8388608;
  size_t base_used = (size_t)(p - (char*)d_ws);
  void* Pws = (void*)p;  // 64MB: f16 scores [b,h,q,k], then bf16 probs in place
  bool fast = (base_used + 67108864ull) <= ws_size;
  (void)kws;

  float* xout = (float*)d_out;
  float* attnf = (float*)d_out + 2097152;  // output 1: [b,q,k,h] f32

  dim3 blk(256);

  // transposes + cast, single launch
  kprep<<<11264, blk, 0, stream>>>(x, xbf, wq, wk, wv, wg, wo, w1, w2, wqT, wkT, wvT, wgT, woT,
                                   w1T, w2T);

  // fused Q|K|V|G projections: M=2048, N=4096, K=1024 (512 blocks -> full GPU)
  gemm_bt<MODE_QKVG><<<dim3(32, 16, 1), blk, 0, stream>>>(xbf, wqT, qws, bg, nullptr, 2048, 4096,
                                                          1024, 1024, 1024, 0, 0, 1.0f);

  if (fast) {
    // scores f16, coalesced [b,h,q,k]
    gemm_bt<MODE_SCOREF16><<<dim3(8, 8, 32), blk, 0, stream>>>(
        qws, kws, Pws, nullptr, nullptr, 1024, 1024, 64, 64, 64, 65536, 65536, 1.0f);
    attn_softmax16<<<2048, blk, 0, stream>>>(attnf, Pws, ebias, pmask);
    gemm_bt<MODE_PV><<<dim3(1, 8, 32), blk, 0, stream>>>((bf16*)Pws, vtws, ows, nullptr, gws,
                                                         1024, 64, 1024, 1024, 1024, 1048576,
                                                         65536, 1.0f);
  } else {
    gemm_bt<MODE_SCORE_SC><<<dim3(8, 8, 32), blk, 0, stream>>>(
        qws, kws, attnf, nullptr, nullptr, 1024, 1024, 64, 64, 64, 65536, 65536, 1.0f);
    attn_softmax<0><<<4096, blk, 0, stream>>>(attnf, nullptr, ebias, pmask);
    gemm_bt<MODE_PV_SLOW><<<dim3(1, 8, 32), blk, 0, stream>>>(attnf, vtws, ows, nullptr, gws,
                                                              1024, 64, 1024, 1024, 1024, 0,
                                                              65536, 1.0f);
  }

  // delta = o @ wo + bo
  gemm_bt<MODE_WO><<<dim3(8, 16, 1), blk, 0, stream>>>(ows, woT, delta, bo, nullptr, 2048, 1024,
                                                       1024, 1024, 1024, 0, 0, 1.0f);
  // x1 = LN1(x + delta)
  layernorm_k<0><<<2048, blk, 0, stream>>>(x, delta, ln1g, ln1b, x1f, x1bf);
  // ffn1 = silu(x1 @ w1 + b1)
  gemm_bt<MODE_FFN1><<<dim3(16, 16, 1), blk, 0, stream>>>(x1bf, w1T, ffn1, b1, nullptr, 2048,
                                                          2048, 1024, 1024, 1024, 0, 0, 1.0f);
  // ffn2 = ffn1 @ w2 + b2
  gemm_bt<MODE_FFN2><<<dim3(8, 16, 1), blk, 0, stream>>>(ffn1, w2T, ffn2, b2, nullptr, 2048, 1024,
                                                         2048, 2048, 2048, 0, 0, 1.0f);
  // out = LN2(x1 + ffn2)
  layernorm_k<1><<<2048, blk, 0, stream>>>(x1f, ffn2, ln2g, ln2b, xout, nullptr);
}

// Round 2
// 559.466 us; speedup vs baseline: 1.2052x; 1.0239x over previous
//
#include <hip/hip_runtime.h>

typedef __bf16 bf16;
typedef _Float16 f16;
typedef bf16 bf16x8 __attribute__((ext_vector_type(8)));
typedef bf16 bf16x4 __attribute__((ext_vector_type(4)));
typedef f16 f16x4 __attribute__((ext_vector_type(4)));
typedef f16 f16x8 __attribute__((ext_vector_type(8)));
typedef float f32x4 __attribute__((ext_vector_type(4)));

// B=2, L=1024, D=1024, H=16, HD=64, FFN=2048, TEMP=8, EPS=1e-5. All I/O f32.

// ---------------------------------------------------------------- prep: 7 transposes + x cast, one kernel
__global__ __launch_bounds__(256) void kprep(
    const float* __restrict__ x, bf16* __restrict__ xbf,
    const float* __restrict__ wq, const float* __restrict__ wk, const float* __restrict__ wv,
    const float* __restrict__ wg, const float* __restrict__ wo, const float* __restrict__ w1,
    const float* __restrict__ w2, bf16* __restrict__ wqT, bf16* __restrict__ wkT,
    bf16* __restrict__ wvT, bf16* __restrict__ wgT, bf16* __restrict__ woT,
    bf16* __restrict__ w1T, bf16* __restrict__ w2T) {
  int bid = blockIdx.x;
  int tid = threadIdx.x;

  if (bid >= 9216) {  // cast segment
    int i = (bid - 9216) * 256 + tid;
    f32x4 v = *(const f32x4*)(x + (long)i * 4);
    bf16x4 o;
#pragma unroll
    for (int j = 0; j < 4; j++) o[j] = (bf16)v[j];
    *(bf16x4*)(xbf + (long)i * 4) = o;
    return;
  }

  __shared__ float t[32][33];
  const float* src;
  bf16* dst;
  int R, C, tile;
  if (bid < 5120) {
    int seg = bid >> 10;
    tile = bid & 1023;
    R = 1024; C = 1024;
    if (seg == 0) { src = wq; dst = wqT; }
    else if (seg == 1) { src = wk; dst = wkT; }
    else if (seg == 2) { src = wv; dst = wvT; }
    else if (seg == 3) { src = wg; dst = wgT; }
    else { src = wo; dst = woT; }
  } else if (bid < 7168) {
    tile = bid - 5120; R = 1024; C = 2048; src = w1; dst = w1T;
  } else {
    tile = bid - 7168; R = 2048; C = 1024; src = w2; dst = w2T;
  }
  int txs = (C == 2048) ? 6 : 5;  // tiles along C
  int c0 = (tile & ((1 << txs) - 1)) << 5, r0 = (tile >> txs) << 5;
  int tx = tid & 31, ty = tid >> 5;
#pragma unroll
  for (int i = 0; i < 32; i += 8)
    t[ty + i][tx] = src[(long)(r0 + ty + i) * C + c0 + tx];
  __syncthreads();
#pragma unroll
  for (int i = 0; i < 32; i += 8)
    dst[(long)(c0 + ty + i) * R + r0 + tx] = (bf16)t[tx][ty + i];
}

// ---------------------------------------------------------------- GEMM (C = A * Bt^T), MFMA bf16
static constexpr int MODE_QK = 0;        // out bf16 [b,h,l,hd], alpha scale
static constexpr int MODE_VT = 1;        // out bf16 [b,h,hd,l]
static constexpr int MODE_G = 2;         // out f32 = sigmoid(acc + bias[n])
static constexpr int MODE_SCOREF16 = 3;  // out f16 [b,h,q,k] contiguous (z = b*16+h)
static constexpr int MODE_SCORE_SC = 4;  // out f32 scattered [b,q,k,h] (fallback)
static constexpr int MODE_PV = 5;        // A=Pws bf16 [b,h,q,k]; out bf16 gated
static constexpr int MODE_PV_SLOW = 6;   // A=attn f32 [b,q,k,h] strided; out bf16 gated
static constexpr int MODE_WO = 7;        // out f32 = acc + bias[n]
static constexpr int MODE_FFN1 = 8;      // out bf16 = silu(acc + bias[n])
static constexpr int MODE_FFN2 = 9;      // out f32 = acc + bias[n]
static constexpr int MODE_QKVG = 10;     // fused Q|K|V|G projections, N=4096; Out=qws base

template <int MODE>
__global__ __launch_bounds__(256) void gemm_bt(
    const void* __restrict__ Av, const bf16* __restrict__ Bt, void* __restrict__ Out,
    const float* __restrict__ bias, const float* __restrict__ gate,
    int M, int N, int K, int lda, int ldb, long sA, long sB, float alpha) {
  const int z = blockIdx.z;
  const bf16* A = (const bf16*)Av + (long)z * sA;
  Bt += (long)z * sB;
  const int bb = z >> 4, hh = z & 15;

  __shared__ bf16 As[128][40];  // 80B row stride -> 2-way (free) on ds_read_b128
  __shared__ bf16 Bs[128][40];

  const int tid = threadIdx.x;
  const int m0 = blockIdx.y * 128, n0 = blockIdx.x * 128;
  const int lane = tid & 63, wave = tid >> 6;
  const int wm = (wave >> 1) * 64, wn = (wave & 1) * 64;
  const int l15 = lane & 15, quad = lane >> 4;

  f32x4 acc[4][4] = {};

  for (int k0 = 0; k0 < K; k0 += 32) {
    bf16x8 av[2], bv[2];
#pragma unroll
    for (int u = 0; u < 2; u++) {
      int c = tid + u * 256;
      int row = c >> 2, kc = (c & 3) << 3;
      if (MODE == MODE_PV_SLOW) {
        const float* Af = (const float*)Av;
        long rb = ((long)bb << 24) + hh + ((long)(m0 + row) << 14) + ((long)(k0 + kc) << 4);
#pragma unroll
        for (int j = 0; j < 8; j++) av[u][j] = (bf16)Af[rb + j * 16];
      } else {
        av[u] = *(const bf16x8*)(A + (long)(m0 + row) * lda + (k0 + kc));
      }
      int brow = n0 + row;
      if (brow < N) {
        bv[u] = *(const bf16x8*)(Bt + (long)brow * ldb + (k0 + kc));
      } else {
#pragma unroll
        for (int j = 0; j < 8; j++) bv[u][j] = (bf16)0.0f;
      }
    }
    __syncthreads();
#pragma unroll
    for (int u = 0; u < 2; u++) {
      int c = tid + u * 256;
      int row = c >> 2, kc = (c & 3) << 3;
      *(bf16x8*)&As[row][kc] = av[u];
      *(bf16x8*)&Bs[row][kc] = bv[u];
    }
    __syncthreads();

    bf16x8 af[4], bfr[4];
#pragma unroll
    for (int t = 0; t < 4; t++) {
      af[t] = *(const bf16x8*)&As[wm + t * 16 + l15][quad << 3];
      bfr[t] = *(const bf16x8*)&Bs[wn + t * 16 + l15][quad << 3];
    }
#pragma unroll
    for (int mt = 0; mt < 4; mt++)
#pragma unroll
      for (int nt = 0; nt < 4; nt++)
        acc[mt][nt] =
            __builtin_amdgcn_mfma_f32_16x16x32_bf16(af[mt], bfr[nt], acc[mt][nt], 0, 0, 0);
  }

  // C/D layout: col=lane&15, row=quad*4+reg
#pragma unroll
  for (int mt = 0; mt < 4; mt++) {
#pragma unroll
    for (int nt = 0; nt < 4; nt++) {
#pragma unroll
      for (int r = 0; r < 4; r++) {
        int m = m0 + wm + mt * 16 + (quad << 2) + r;
        int n = n0 + wn + nt * 16 + l15;
        if (n >= N) continue;  // only PV (N=64)
        float v = acc[mt][nt][r] * alpha;
        if (MODE == MODE_QK) {
          long off = ((long)((m >> 10) * 16 + (n >> 6)) * 1024 + (m & 1023)) * 64 + (n & 63);
          ((bf16*)Out)[off] = (bf16)v;
        } else if (MODE == MODE_VT) {
          long off = ((long)((m >> 10) * 16 + (n >> 6)) * 64 + (n & 63)) * 1024 + (m & 1023);
          ((bf16*)Out)[off] = (bf16)v;
        } else if (MODE == MODE_G) {
          float t = v + bias[n];
          ((float*)Out)[(long)m * N + n] = 1.0f / (1.0f + __expf(-t));
        } else if (MODE == MODE_QKVG) {
          int sec = n >> 10, nn = n & 1023;
          bf16* ob = (bf16*)Out;  // qws base; kws/vtws/gws contiguous after it
          if (sec == 0) {
            long off = ((long)((m >> 10) * 16 + (nn >> 6)) * 1024 + (m & 1023)) * 64 + (nn & 63);
            ob[off] = (bf16)(v * 0.125f);
          } else if (sec == 1) {
            long off = ((long)((m >> 10) * 16 + (nn >> 6)) * 1024 + (m & 1023)) * 64 + (nn & 63);
            (ob + 2097152)[off] = (bf16)v;
          } else if (sec == 2) {
            long off = ((long)((m >> 10) * 16 + (nn >> 6)) * 64 + (nn & 63)) * 1024 + (m & 1023);
            (ob + 4194304)[off] = (bf16)v;
          } else {
            float t = v + bias[nn];
            ((float*)(ob + 6291456))[(long)m * 1024 + nn] = 1.0f / (1.0f + __expf(-t));
          }
        } else if (MODE == MODE_SCOREF16) {
          ((f16*)Out)[((long)z << 20) + ((long)m << 10) + n] = (f16)v;
        } else if (MODE == MODE_SCORE_SC) {
          long off = ((long)bb << 24) + ((long)m << 14) + ((long)n << 4) + hh;
          ((float*)Out)[off] = v;
        } else if (MODE == MODE_PV || MODE == MODE_PV_SLOW) {
          long off = ((long)(bb * 1024 + m)) * 1024 + hh * 64 + n;
          ((bf16*)Out)[off] = (bf16)(v * gate[off]);
        } else if (MODE == MODE_WO) {
          ((float*)Out)[(long)m * N + n] = v + bias[n];
        } else if (MODE == MODE_FFN1) {
          float t = v + bias[n];
          ((bf16*)Out)[(long)m * N + n] = (bf16)(t / (1.0f + __expf(-t)));
        } else {  // MODE_FFN2
          ((float*)Out)[(long)m * N + n] = v + bias[n];
        }
      }
    }
  }
}

// ---------------------------------------------------------------- bias + softmax, ALL 16 heads per (b,q)
// f16 LDS bias/P buffer (33KB -> 4 blocks/CU). Scores read directly from global (L3-hot),
// P written straight back over the f16 scores as bf16 + staged in LDS for the attnf transpose.
__global__ __launch_bounds__(256, 4) void attn_softmax16(float* __restrict__ attnf,
                                                         void* __restrict__ Sf,
                                                         const float* __restrict__ ebias,
                                                         const unsigned char* __restrict__ mask) {
  // row stride 1032 f16 = 2064B: 16B-aligned rows, bank coeff 4 -> all phases <=2-way
  __shared__ f16 sm[16][1032];
  int bx = blockIdx.x;
  int q = bx & 1023, b = bx >> 10;
  int tid = threadIdx.x;
  int lane = tid & 63, wave = tid >> 6;
  long sbase = ((long)b << 24) + ((long)q << 14);  // [b,q,k,h] slice base (floats)

  // ---- phase 1: ebias [k,h] -> LDS f16 [h][k], write-only scatter, mask folded in.
  // thread owns (h = tid&15, 16-k chunk): global reads lane-coalesced (lanes 0-15 = one line),
  // LDS writes 2x ds_write_b128, 2-way (free).
  {
    int h = tid & 15;
    int kb = (tid >> 4) << 4;  // 0..240
#pragma unroll
    for (int it = 0; it < 4; it++) {
      int k0 = kb + it * 256;
      unsigned mw[4];
      *(uint4*)mw = *(const uint4*)(mask + (b << 10) + k0);
      f16 hv[16];
#pragma unroll
      for (int i = 0; i < 16; i++) {
        float v = ebias[sbase + (long)(k0 + i) * 16 + h];
        bool msk = (mw[i >> 2] >> ((i & 3) * 8)) & 255;
        hv[i] = msk ? (f16)(-60000.0f) : (f16)v;
      }
      *(f16x8*)&sm[h][k0] = *(f16x8*)&hv[0];
      *(f16x8*)&sm[h][k0 + 8] = *(f16x8*)&hv[8];
    }
  }

  // prefetch this wave's 4 score rows (global f16, L3-hot) before the barrier
  f16* S = (f16*)Sf;
  f16x8 sv[4][2];
#pragma unroll
  for (int hi = 0; hi < 4; hi++) {
    int h = wave * 4 + hi;
    long srow = (((long)((b << 4) + h) << 10) + q) << 10;
    sv[hi][0] = *(const f16x8*)(S + srow + lane * 8);
    sv[hi][1] = *(const f16x8*)(S + srow + lane * 8 + 512);
  }
  __syncthreads();

  // ---- phase 2: per-wave softmax over 4 heads; P -> Pws (bf16, in-place) + LDS f16
#pragma unroll
  for (int hi = 0; hi < 4; hi++) {
    int h = wave * 4 + hi;
    long srow = (((long)((b << 4) + h) << 10) + q) << 10;
    f16x8 bv0 = *(const f16x8*)&sm[h][lane * 8];
    f16x8 bv1 = *(const f16x8*)&sm[h][lane * 8 + 512];
    float s_[16];
#pragma unroll
    for (int j = 0; j < 8; j++) {
      s_[j] = (float)sv[hi][0][j] + (float)bv0[j];
      s_[8 + j] = (float)sv[hi][1][j] + (float)bv1[j];
    }
    float mx = s_[0];
#pragma unroll
    for (int j = 1; j < 16; j++) mx = fmaxf(mx, s_[j]);
#pragma unroll
    for (int d = 32; d; d >>= 1) mx = fmaxf(mx, __shfl_xor(mx, d, 64));
    float sum = 0.f;
#pragma unroll
    for (int j = 0; j < 16; j++) {
      s_[j] = __expf(s_[j] - mx);
      sum += s_[j];
    }
#pragma unroll
    for (int d = 32; d; d >>= 1) sum += __shfl_xor(sum, d, 64);
    float inv = 1.0f / sum;
    bf16x8 pb0, pb1;
    f16 ph[16];
#pragma unroll
    for (int j = 0; j < 16; j++) {
      float pv = s_[j] * inv;
      ph[j] = (f16)pv;
      if (j < 8) pb0[j] = (bf16)pv; else pb1[j - 8] = (bf16)pv;
    }
    *(bf16x8*)((bf16*)Sf + srow + lane * 8) = pb0;
    *(bf16x8*)((bf16*)Sf + srow + lane * 8 + 512) = pb1;
    *(f16x8*)&sm[h][lane * 8] = *(f16x8*)&ph[0];
    *(f16x8*)&sm[h][lane * 8 + 512] = *(f16x8*)&ph[8];
  }
  __syncthreads();

  // ---- phase 3: attnf f32 [b,q,k,h] transpose-out (coalesced stores; LDS reads word-broadcast)
#pragma unroll
  for (int it = 0; it < 16; it++) {
    int j = tid + it * 256;
    int k = j >> 2, c = (j & 3) << 2;
    f32x4 v;
#pragma unroll
    for (int jj = 0; jj < 4; jj++) v[jj] = (float)sm[c + jj][k];
    *(f32x4*)(attnf + sbase + ((long)k << 4) + c) = v;
  }
}

// ---------------------------------------------------------------- bias + softmax (fallback, f32 scattered)
template <int FAST>
__global__ __launch_bounds__(256) void attn_softmax(float* __restrict__ attnf,
                                                    void* __restrict__ Sf,
                                                    const float* __restrict__ ebias,
                                                    const unsigned char* __restrict__ mask) {
  __shared__ float sm[8][1028];
  int bx = blockIdx.x;
  int hb = (bx & 1) * 8;
  int q = (bx >> 1) & 1023;
  int b = bx >> 11;
  int tid = threadIdx.x;
  int lane = tid & 63, wave = tid >> 6;
  long sbase = ((long)b << 24) + ((long)q << 14) + hb;  // [b,q,k,h] slice base

  for (int i = tid; i < 2048; i += 256) {
    int k = i >> 1, c = (i & 1) * 4;
    long off = sbase + ((long)k << 4) + c;
    f32x4 s = *(const f32x4*)(attnf + off);
    f32x4 e = *(const f32x4*)(ebias + off);
#pragma unroll
    for (int j = 0; j < 4; j++) sm[c + j][k] = s[j] + e[j];
  }
  __syncthreads();

  for (int k = tid; k < 1024; k += 256) {
    if (mask[(b << 10) + k]) {
#pragma unroll
      for (int h = 0; h < 8; h++) sm[h][k] = -1e30f;
    }
  }
  __syncthreads();

  for (int h = wave * 2; h < wave * 2 + 2; h++) {
    float mx = -1e30f;
    for (int k = lane; k < 1024; k += 64) mx = fmaxf(mx, sm[h][k]);
#pragma unroll
    for (int d = 32; d; d >>= 1) mx = fmaxf(mx, __shfl_xor(mx, d, 64));
    float sum = 0.f;
    for (int k = lane; k < 1024; k += 64) {
      float p = __expf(sm[h][k] - mx);
      sm[h][k] = p;
      sum += p;
    }
#pragma unroll
    for (int d = 32; d; d >>= 1) sum += __shfl_xor(sum, d, 64);
    float inv = 1.0f / sum;
    for (int k = lane; k < 1024; k += 64) sm[h][k] *= inv;
  }
  __syncthreads();

  for (int i = tid; i < 2048; i += 256) {
    int k = i >> 1, c = (i & 1) * 4;
    f32x4 v;
#pragma unroll
    for (int j = 0; j < 4; j++) v[j] = sm[c + j][k];
    *(f32x4*)(attnf + sbase + ((long)k << 4) + c) = v;
  }
}

// ---------------------------------------------------------------- layernorm (1024 cols)
template <int MODE>
__global__ __launch_bounds__(256) void layernorm_k(
    const float* __restrict__ a32, const float* __restrict__ b32, const float* __restrict__ g,
    const float* __restrict__ be, float* __restrict__ of32, bf16* __restrict__ obf) {
  __shared__ float red[8];
  long base = (long)blockIdx.x << 10;
  int tid = threadIdx.x;
  int lane = tid & 63, wave = tid >> 6;
  float h[4], sum = 0.f, sq = 0.f;
#pragma unroll
  for (int t = 0; t < 4; t++) {
    int i = tid + t * 256;
    float v = a32[base + i] + b32[base + i];
    h[t] = v;
    sum += v;
    sq += v * v;
  }
#pragma unroll
  for (int d = 32; d; d >>= 1) {
    sum += __shfl_xor(sum, d, 64);
    sq += __shfl_xor(sq, d, 64);
  }
  if (lane == 0) { red[wave] = sum; red[4 + wave] = sq; }
  __syncthreads();
  sum = red[0] + red[1] + red[2] + red[3];
  sq = red[4] + red[5] + red[6] + red[7];
  float mean = sum * (1.0f / 1024.0f);
  float var = sq * (1.0f / 1024.0f) - mean * mean;
  float rstd = rsqrtf(var + 1e-5f);
#pragma unroll
  for (int t = 0; t < 4; t++) {
    int i = tid + t * 256;
    float o = (h[t] - mean) * rstd * g[i] + be[i];
    of32[base + i] = o;
    if (MODE == 0) obf[base + i] = (bf16)o;
  }
}

// ---------------------------------------------------------------- launch
extern "C" void kernel_launch(void* const* d_in, const int* in_sizes, int n_in, void* d_out,
                              int out_size, void* d_ws, size_t ws_size, hipStream_t stream) {
  const float* x = (const float*)d_in[0];
  const float* ebias = (const float*)d_in[1];
  const unsigned char* pmask = (const unsigned char*)d_in[2];
  const float* wq = (const float*)d_in[3];
  const float* wk = (const float*)d_in[4];
  const float* wv = (const float*)d_in[5];
  const float* wo = (const float*)d_in[6];
  const float* bo = (const float*)d_in[7];
  const float* wg = (const float*)d_in[8];
  const float* bg = (const float*)d_in[9];
  const float* w1 = (const float*)d_in[10];
  const float* b1 = (const float*)d_in[11];
  const float* w2 = (const float*)d_in[12];
  const float* b2 = (const float*)d_in[13];
  const float* ln1g = (const float*)d_in[14];
  const float* ln1b = (const float*)d_in[15];
  const float* ln2g = (const float*)d_in[16];
  const float* ln2b = (const float*)d_in[17];

  char* p = (char*)d_ws;
  bf16* xbf = (bf16*)p;  p += 4194304;
  bf16* wqT = (bf16*)p;  p += 2097152;   // wqT/wkT/wvT/wgT contiguous -> one [4096][1024] B matrix
  bf16* wkT = (bf16*)p;  p += 2097152;
  bf16* wvT = (bf16*)p;  p += 2097152;
  bf16* wgT = (bf16*)p;  p += 2097152;
  bf16* woT = (bf16*)p;  p += 2097152;
  bf16* w1T = (bf16*)p;  p += 4194304;
  bf16* w2T = (bf16*)p;  p += 4194304;
  bf16* qws = (bf16*)p;  p += 4194304;    // [b,h,l,hd]   (QKVG epilogue writes kws/vtws/gws via offsets)
  bf16* kws = (bf16*)p;  p += 4194304;    // [b,h,l,hd]
  bf16* vtws = (bf16*)p; p += 4194304;    // [b,h,hd,l]
  float* gws = (float*)p; p += 8388608;   // sigmoid gate f32
  bf16* ows = (bf16*)p;  p += 4194304;
  float* delta = (float*)p; p += 8388608;
  bf16* x1bf = (bf16*)p; p += 4194304;
  float* x1f = (float*)p; p += 8388608;
  bf16* ffn1 = (bf16*)p; p += 8388608;
  float* ffn2 = (float*)p; p += 8388608;
  size_t base_used = (size_t)(p - (char*)d_ws);
  void* Pws = (void*)p;  // 64MB: f16 scores [b,h,q,k], then bf16 probs in place
  bool fast = (base_used + 67108864ull) <= ws_size;
  (void)kws;

  float* xout = (float*)d_out;
  float* attnf = (float*)d_out + 2097152;  // output 1: [b,q,k,h] f32

  dim3 blk(256);

  // transposes + cast, single launch
  kprep<<<11264, blk, 0, stream>>>(x, xbf, wq, wk, wv, wg, wo, w1, w2, wqT, wkT, wvT, wgT, woT,
                                   w1T, w2T);

  // fused Q|K|V|G projections: M=2048, N=4096, K=1024 (512 blocks -> full GPU)
  gemm_bt<MODE_QKVG><<<dim3(32, 16, 1), blk, 0, stream>>>(xbf, wqT, qws, bg, nullptr, 2048, 4096,
                                                          1024, 1024, 1024, 0, 0, 1.0f);

  if (fast) {
    // scores f16, coalesced [b,h,q,k]
    gemm_bt<MODE_SCOREF16><<<dim3(8, 8, 32), blk, 0, stream>>>(
        qws, kws, Pws, nullptr, nullptr, 1024, 1024, 64, 64, 64, 65536, 65536, 1.0f);
    attn_softmax16<<<2048, blk, 0, stream>>>(attnf, Pws, ebias, pmask);
    gemm_bt<MODE_PV><<<dim3(1, 8, 32), blk, 0, stream>>>((bf16*)Pws, vtws, ows, nullptr, gws,
                                                         1024, 64, 1024, 1024, 1024, 1048576,
                                                         65536, 1.0f);
  } else {
    gemm_bt<MODE_SCORE_SC><<<dim3(8, 8, 32), blk, 0, stream>>>(
        qws, kws, attnf, nullptr, nullptr, 1024, 1024, 64, 64, 64, 65536, 65536, 1.0f);
    attn_softmax<0><<<4096, blk, 0, stream>>>(attnf, nullptr, ebias, pmask);
    gemm_bt<MODE_PV_SLOW><<<dim3(1, 8, 32), blk, 0, stream>>>(attnf, vtws, ows, nullptr, gws,
                                                              1024, 64, 1024, 1024, 1024, 0,
                                                              65536, 1.0f);
  }

  // delta = o @ wo + bo
  gemm_bt<MODE_WO><<<dim3(8, 16, 1), blk, 0, stream>>>(ows, woT, delta, bo, nullptr, 2048, 1024,
                                                       1024, 1024, 1024, 0, 0, 1.0f);
  // x1 = LN1(x + delta)
  layernorm_k<0><<<2048, blk, 0, stream>>>(x, delta, ln1g, ln1b, x1f, x1bf);
  // ffn1 = silu(x1 @ w1 + b1)
  gemm_bt<MODE_FFN1><<<dim3(16, 16, 1), blk, 0, stream>>>(x1bf, w1T, ffn1, b1, nullptr, 2048,
                                                          2048, 1024, 1024, 1024, 0, 0, 1.0f);
  // ffn2 = ffn1 @ w2 + b2
  gemm_bt<MODE_FFN2><<<dim3(8, 16, 1), blk, 0, stream>>>(ffn1, w2T, ffn2, b2, nullptr, 2048, 1024,
                                                         2048, 2048, 2048, 0, 0, 1.0f);
  // out = LN2(x1 + ffn2)
  layernorm_k<1><<<2048, blk, 0, stream>>>(x1f, ffn2, ln2g, ln2b, xout, nullptr);
}

// Round 3
// 527.536 us; speedup vs baseline: 1.2782x; 1.0605x over previous
//
#include <hip/hip_runtime.h>

typedef __bf16 bf16;
typedef _Float16 f16;
typedef bf16 bf16x8 __attribute__((ext_vector_type(8)));
typedef bf16 bf16x4 __attribute__((ext_vector_type(4)));
typedef f16 f16x4 __attribute__((ext_vector_type(4)));
typedef f16 f16x8 __attribute__((ext_vector_type(8)));
typedef float f32x4 __attribute__((ext_vector_type(4)));

// B=2, L=1024, D=1024, H=16, HD=64, FFN=2048, TEMP=8, EPS=1e-5. All I/O f32.

// async global->LDS, 16B per lane. LDS dest = wave-uniform base + lane*16.
__device__ __forceinline__ void gload16(const bf16* g, bf16* l) {
  __builtin_amdgcn_global_load_lds((const __attribute__((address_space(1))) unsigned int*)g,
                                   (__attribute__((address_space(3))) unsigned int*)l, 16, 0, 0);
}

// ---------------------------------------------------------------- prep: 7 transposes + x cast, one kernel
__global__ __launch_bounds__(256) void kprep(
    const float* __restrict__ x, bf16* __restrict__ xbf,
    const float* __restrict__ wq, const float* __restrict__ wk, const float* __restrict__ wv,
    const float* __restrict__ wg, const float* __restrict__ wo, const float* __restrict__ w1,
    const float* __restrict__ w2, bf16* __restrict__ wqT, bf16* __restrict__ wkT,
    bf16* __restrict__ wvT, bf16* __restrict__ wgT, bf16* __restrict__ woT,
    bf16* __restrict__ w1T, bf16* __restrict__ w2T) {
  int bid = blockIdx.x;
  int tid = threadIdx.x;

  if (bid >= 9216) {  // cast segment
    int i = (bid - 9216) * 256 + tid;
    f32x4 v = *(const f32x4*)(x + (long)i * 4);
    bf16x4 o;
#pragma unroll
    for (int j = 0; j < 4; j++) o[j] = (bf16)v[j];
    *(bf16x4*)(xbf + (long)i * 4) = o;
    return;
  }

  __shared__ float t[32][33];
  const float* src;
  bf16* dst;
  int R, C, tile;
  if (bid < 5120) {
    int seg = bid >> 10;
    tile = bid & 1023;
    R = 1024; C = 1024;
    if (seg == 0) { src = wq; dst = wqT; }
    else if (seg == 1) { src = wk; dst = wkT; }
    else if (seg == 2) { src = wv; dst = wvT; }
    else if (seg == 3) { src = wg; dst = wgT; }
    else { src = wo; dst = woT; }
  } else if (bid < 7168) {
    tile = bid - 5120; R = 1024; C = 2048; src = w1; dst = w1T;
  } else {
    tile = bid - 7168; R = 2048; C = 1024; src = w2; dst = w2T;
  }
  int txs = (C == 2048) ? 6 : 5;  // tiles along C
  int c0 = (tile & ((1 << txs) - 1)) << 5, r0 = (tile >> txs) << 5;
  int tx = tid & 31, ty = tid >> 5;
#pragma unroll
  for (int i = 0; i < 32; i += 8)
    t[ty + i][tx] = src[(long)(r0 + ty + i) * C + c0 + tx];
  __syncthreads();
#pragma unroll
  for (int i = 0; i < 32; i += 8)
    dst[(long)(c0 + ty + i) * R + r0 + tx] = (bf16)t[tx][ty + i];
}

// ---------------------------------------------------------------- GEMM (C = A * Bt^T), MFMA bf16
// m97 structure: linear LDS [rows][32] bf16, global_load_lds dwordx4 staging, 2 barriers/iter.
static constexpr int MODE_QK = 0;        // out bf16 [b,h,l,hd], alpha scale
static constexpr int MODE_VT = 1;        // out bf16 [b,h,hd,l]
static constexpr int MODE_G = 2;         // (unused, folded into QKVG)
static constexpr int MODE_SCOREF16 = 3;  // out f16 [b,h,q,k] contiguous (z = b*16+h)
static constexpr int MODE_SCORE_SC = 4;  // out f32 scattered [b,q,k,h] (fallback)
static constexpr int MODE_PV = 5;        // A=Pws bf16 [b,h,q,k]; out bf16 gated
static constexpr int MODE_PV_SLOW = 6;   // A=attn f32 [b,q,k,h] strided; out bf16 gated
static constexpr int MODE_WO = 7;        // out f32 = acc + bias[n]
static constexpr int MODE_FFN1 = 8;      // out bf16 = silu(acc + bias[n])
static constexpr int MODE_FFN2 = 9;      // out f32 = acc + bias[n]
static constexpr int MODE_QKVG = 10;     // fused Q|K|V|G projections, N=4096; Out=qws base

template <int MODE, int BN>
__global__ __launch_bounds__(256) void gemm_bt(
    const void* __restrict__ Av, const bf16* __restrict__ Bt, void* __restrict__ Out,
    const float* __restrict__ bias, const float* __restrict__ gate,
    int M, int N, int K, int lda, int ldb, long sA, long sB, float alpha) {
  const int z = blockIdx.z;
  const bf16* A = (const bf16*)Av + (long)z * sA;
  Bt += (long)z * sB;
  const int bb = z >> 4, hh = z & 15;

  constexpr int NT = (BN == 128) ? 4 : 2;
  __shared__ bf16 As[128 * 32];  // linear: global_load_lds needs contiguous lane-order dest
  __shared__ bf16 Bs[BN * 32];

  const int tid = threadIdx.x;
  const int m0 = blockIdx.y * 128, n0 = blockIdx.x * BN;
  const int lane = tid & 63, wave = tid >> 6;
  const int wm = (wave >> 1) * 64;
  const int wn = (BN == 128) ? (wave & 1) * 64 : (wave & 1) * 32;
  const int l15 = lane & 15, quad = lane >> 4;

  // staging geometry: chunk = 16B = 8 bf16; row = chunk>>2, kc = (chunk&3)*8
  const int srow = (lane >> 2);          // 0..15 within a wave-instr
  const int skc = (lane & 3) << 3;       // 0,8,16,24

  f32x4 acc[4][NT] = {};

  for (int k0 = 0; k0 < K; k0 += 32) {
    if (MODE == MODE_PV_SLOW) {
      // fallback: strided f32 A gather -> regs; B -> regs; ds_write into linear LDS
      bf16x8 av[2], bv;
#pragma unroll
      for (int u = 0; u < 2; u++) {
        int c = tid + u * 256;
        int row = c >> 2, kc = (c & 3) << 3;
        const float* Af = (const float*)Av;
        long rb = ((long)bb << 24) + hh + ((long)(m0 + row) << 14) + ((long)(k0 + kc) << 4);
#pragma unroll
        for (int j = 0; j < 8; j++) av[u][j] = (bf16)Af[rb + j * 16];
      }
      bv = *(const bf16x8*)(Bt + (long)(n0 + (tid >> 2)) * ldb + (k0 + ((tid & 3) << 3)));
      __syncthreads();
#pragma unroll
      for (int u = 0; u < 2; u++) {
        int c = tid + u * 256;
        *(bf16x8*)&As[c * 8] = av[u];
      }
      *(bf16x8*)&Bs[tid * 8] = bv;
    } else {
      __syncthreads();  // all waves done reading LDS from previous iter
      // A: 128x32 = 8KB, 2 instrs/wave
      gload16(A + (long)(m0 + wave * 32 + srow) * lda + (k0 + skc), As + (wave * 2 + 0) * 512);
      gload16(A + (long)(m0 + wave * 32 + 16 + srow) * lda + (k0 + skc),
              As + (wave * 2 + 1) * 512);
      if (BN == 128) {
        gload16(Bt + (long)(n0 + wave * 32 + srow) * ldb + (k0 + skc), Bs + (wave * 2 + 0) * 512);
        gload16(Bt + (long)(n0 + wave * 32 + 16 + srow) * ldb + (k0 + skc),
                Bs + (wave * 2 + 1) * 512);
      } else {
        gload16(Bt + (long)(n0 + wave * 16 + srow) * ldb + (k0 + skc), Bs + wave * 512);
      }
    }
    __syncthreads();  // drains vmcnt (DMA) / lgkmcnt (writes) then barrier

    bf16x8 af[4], bfr[NT];
#pragma unroll
    for (int t = 0; t < 4; t++)
      af[t] = *(const bf16x8*)&As[(wm + t * 16 + l15) * 32 + (quad << 3)];
#pragma unroll
    for (int t = 0; t < NT; t++)
      bfr[t] = *(const bf16x8*)&Bs[(wn + t * 16 + l15) * 32 + (quad << 3)];
#pragma unroll
    for (int mt = 0; mt < 4; mt++)
#pragma unroll
      for (int nt = 0; nt < NT; nt++)
        acc[mt][nt] =
            __builtin_amdgcn_mfma_f32_16x16x32_bf16(af[mt], bfr[nt], acc[mt][nt], 0, 0, 0);
    if (MODE == MODE_PV_SLOW) __syncthreads();
  }

  // C/D layout: col=lane&15, row=quad*4+reg
#pragma unroll
  for (int mt = 0; mt < 4; mt++) {
#pragma unroll
    for (int nt = 0; nt < NT; nt++) {
#pragma unroll
      for (int r = 0; r < 4; r++) {
        int m = m0 + wm + mt * 16 + (quad << 2) + r;
        int n = n0 + wn + nt * 16 + l15;
        float v = acc[mt][nt][r] * alpha;
        if (MODE == MODE_QK) {
          long off = ((long)((m >> 10) * 16 + (n >> 6)) * 1024 + (m & 1023)) * 64 + (n & 63);
          ((bf16*)Out)[off] = (bf16)v;
        } else if (MODE == MODE_VT) {
          long off = ((long)((m >> 10) * 16 + (n >> 6)) * 64 + (n & 63)) * 1024 + (m & 1023);
          ((bf16*)Out)[off] = (bf16)v;
        } else if (MODE == MODE_QKVG) {
          int sec = n >> 10, nn = n & 1023;
          bf16* ob = (bf16*)Out;  // qws base; kws/vtws/gws contiguous after it
          if (sec == 0) {
            long off = ((long)((m >> 10) * 16 + (nn >> 6)) * 1024 + (m & 1023)) * 64 + (nn & 63);
            ob[off] = (bf16)(v * 0.125f);
          } else if (sec == 1) {
            long off = ((long)((m >> 10) * 16 + (nn >> 6)) * 1024 + (m & 1023)) * 64 + (nn & 63);
            (ob + 2097152)[off] = (bf16)v;
          } else if (sec == 2) {
            long off = ((long)((m >> 10) * 16 + (nn >> 6)) * 64 + (nn & 63)) * 1024 + (m & 1023);
            (ob + 4194304)[off] = (bf16)v;
          } else {
            float t = v + bias[nn];
            ((float*)(ob + 6291456))[(long)m * 1024 + nn] = 1.0f / (1.0f + __expf(-t));
          }
        } else if (MODE == MODE_SCOREF16) {
          ((f16*)Out)[((long)z << 20) + ((long)m << 10) + n] = (f16)v;
        } else if (MODE == MODE_SCORE_SC) {
          long off = ((long)bb << 24) + ((long)m << 14) + ((long)n << 4) + hh;
          ((float*)Out)[off] = v;
        } else if (MODE == MODE_PV || MODE == MODE_PV_SLOW) {
          long off = ((long)(bb * 1024 + m)) * 1024 + hh * 64 + n;
          ((bf16*)Out)[off] = (bf16)(v * gate[off]);
        } else if (MODE == MODE_WO) {
          ((float*)Out)[(long)m * N + n] = v + bias[n];
        } else if (MODE == MODE_FFN1) {
          float t = v + bias[n];
          ((bf16*)Out)[(long)m * N + n] = (bf16)(t / (1.0f + __expf(-t)));
        } else if (MODE == MODE_FFN2) {
          ((float*)Out)[(long)m * N + n] = v + bias[n];
        }
      }
    }
  }
}

// ---------------------------------------------------------------- bias + softmax, ALL 16 heads per (b,q)
__global__ __launch_bounds__(256, 4) void attn_softmax16(float* __restrict__ attnf,
                                                         void* __restrict__ Sf,
                                                         const float* __restrict__ ebias,
                                                         const unsigned char* __restrict__ mask) {
  // row stride 1032 f16 = 2064B: 16B-aligned rows, bank coeff 4 -> all phases <=2-way
  __shared__ f16 sm[16][1032];
  int bx = blockIdx.x;
  int q = bx & 1023, b = bx >> 10;
  int tid = threadIdx.x;
  int lane = tid & 63, wave = tid >> 6;
  long sbase = ((long)b << 24) + ((long)q << 14);  // [b,q,k,h] slice base (floats)

  // ---- phase 1: ebias [k,h] -> LDS f16 [h][k], write-only scatter, mask folded in.
  {
    int h = tid & 15;
    int kb = (tid >> 4) << 4;  // 0..240
#pragma unroll
    for (int it = 0; it < 4; it++) {
      int k0 = kb + it * 256;
      unsigned mw[4];
      *(uint4*)mw = *(const uint4*)(mask + (b << 10) + k0);
      f16 hv[16];
#pragma unroll
      for (int i = 0; i < 16; i++) {
        float v = ebias[sbase + (long)(k0 + i) * 16 + h];
        bool msk = (mw[i >> 2] >> ((i & 3) * 8)) & 255;
        hv[i] = msk ? (f16)(-60000.0f) : (f16)v;
      }
      *(f16x8*)&sm[h][k0] = *(f16x8*)&hv[0];
      *(f16x8*)&sm[h][k0 + 8] = *(f16x8*)&hv[8];
    }
  }

  // prefetch this wave's 4 score rows (global f16, L3-hot) before the barrier
  f16* S = (f16*)Sf;
  f16x8 sv[4][2];
#pragma unroll
  for (int hi = 0; hi < 4; hi++) {
    int h = wave * 4 + hi;
    long srow = (((long)((b << 4) + h) << 10) + q) << 10;
    sv[hi][0] = *(const f16x8*)(S + srow + lane * 8);
    sv[hi][1] = *(const f16x8*)(S + srow + lane * 8 + 512);
  }
  __syncthreads();

  // ---- phase 2: per-wave softmax over 4 heads; P -> Pws (bf16, in-place) + LDS f16
#pragma unroll
  for (int hi = 0; hi < 4; hi++) {
    int h = wave * 4 + hi;
    long srow = (((long)((b << 4) + h) << 10) + q) << 10;
    f16x8 bv0 = *(const f16x8*)&sm[h][lane * 8];
    f16x8 bv1 = *(const f16x8*)&sm[h][lane * 8 + 512];
    float s_[16];
#pragma unroll
    for (int j = 0; j < 8; j++) {
      s_[j] = (float)sv[hi][0][j] + (float)bv0[j];
      s_[8 + j] = (float)sv[hi][1][j] + (float)bv1[j];
    }
    float mx = s_[0];
#pragma unroll
    for (int j = 1; j < 16; j++) mx = fmaxf(mx, s_[j]);
#pragma unroll
    for (int d = 32; d; d >>= 1) mx = fmaxf(mx, __shfl_xor(mx, d, 64));
    float sum = 0.f;
#pragma unroll
    for (int j = 0; j < 16; j++) {
      s_[j] = __expf(s_[j] - mx);
      sum += s_[j];
    }
#pragma unroll
    for (int d = 32; d; d >>= 1) sum += __shfl_xor(sum, d, 64);
    float inv = 1.0f / sum;
    bf16x8 pb0, pb1;
    f16 ph[16];
#pragma unroll
    for (int j = 0; j < 16; j++) {
      float pv = s_[j] * inv;
      ph[j] = (f16)pv;
      if (j < 8) pb0[j] = (bf16)pv; else pb1[j - 8] = (bf16)pv;
    }
    *(bf16x8*)((bf16*)Sf + srow + lane * 8) = pb0;
    *(bf16x8*)((bf16*)Sf + srow + lane * 8 + 512) = pb1;
    *(f16x8*)&sm[h][lane * 8] = *(f16x8*)&ph[0];
    *(f16x8*)&sm[h][lane * 8 + 512] = *(f16x8*)&ph[8];
  }
  __syncthreads();

  // ---- phase 3: attnf f32 [b,q,k,h] transpose-out (coalesced stores; LDS reads word-broadcast)
#pragma unroll
  for (int it = 0; it < 16; it++) {
    int j = tid + it * 256;
    int k = j >> 2, c = (j & 3) << 2;
    f32x4 v;
#pragma unroll
    for (int jj = 0; jj < 4; jj++) v[jj] = (float)sm[c + jj][k];
    *(f32x4*)(attnf + sbase + ((long)k << 4) + c) = v;
  }
}

// ---------------------------------------------------------------- bias + softmax (fallback, f32 scattered)
template <int FAST>
__global__ __launch_bounds__(256) void attn_softmax(float* __restrict__ attnf,
                                                    void* __restrict__ Sf,
                                                    const float* __restrict__ ebias,
                                                    const unsigned char* __restrict__ mask) {
  __shared__ float sm[8][1028];
  int bx = blockIdx.x;
  int hb = (bx & 1) * 8;
  int q = (bx >> 1) & 1023;
  int b = bx >> 11;
  int tid = threadIdx.x;
  int lane = tid & 63, wave = tid >> 6;
  long sbase = ((long)b << 24) + ((long)q << 14) + hb;  // [b,q,k,h] slice base

  for (int i = tid; i < 2048; i += 256) {
    int k = i >> 1, c = (i & 1) * 4;
    long off = sbase + ((long)k << 4) + c;
    f32x4 s = *(const f32x4*)(attnf + off);
    f32x4 e = *(const f32x4*)(ebias + off);
#pragma unroll
    for (int j = 0; j < 4; j++) sm[c + j][k] = s[j] + e[j];
  }
  __syncthreads();

  for (int k = tid; k < 1024; k += 256) {
    if (mask[(b << 10) + k]) {
#pragma unroll
      for (int h = 0; h < 8; h++) sm[h][k] = -1e30f;
    }
  }
  __syncthreads();

  for (int h = wave * 2; h < wave * 2 + 2; h++) {
    float mx = -1e30f;
    for (int k = lane; k < 1024; k += 64) mx = fmaxf(mx, sm[h][k]);
#pragma unroll
    for (int d = 32; d; d >>= 1) mx = fmaxf(mx, __shfl_xor(mx, d, 64));
    float sum = 0.f;
    for (int k = lane; k < 1024; k += 64) {
      float p = __expf(sm[h][k] - mx);
      sm[h][k] = p;
      sum += p;
    }
#pragma unroll
    for (int d = 32; d; d >>= 1) sum += __shfl_xor(sum, d, 64);
    float inv = 1.0f / sum;
    for (int k = lane; k < 1024; k += 64) sm[h][k] *= inv;
  }
  __syncthreads();

  for (int i = tid; i < 2048; i += 256) {
    int k = i >> 1, c = (i & 1) * 4;
    f32x4 v;
#pragma unroll
    for (int j = 0; j < 4; j++) v[j] = sm[c + j][k];
    *(f32x4*)(attnf + sbase + ((long)k << 4) + c) = v;
  }
}

// ---------------------------------------------------------------- layernorm (1024 cols)
template <int MODE>
__global__ __launch_bounds__(256) void layernorm_k(
    const float* __restrict__ a32, const float* __restrict__ b32, const float* __restrict__ g,
    const float* __restrict__ be, float* __restrict__ of32, bf16* __restrict__ obf) {
  __shared__ float red[8];
  long base = (long)blockIdx.x << 10;
  int tid = threadIdx.x;
  int lane = tid & 63, wave = tid >> 6;
  float h[4], sum = 0.f, sq = 0.f;
#pragma unroll
  for (int t = 0; t < 4; t++) {
    int i = tid + t * 256;
    float v = a32[base + i] + b32[base + i];
    h[t] = v;
    sum += v;
    sq += v * v;
  }
#pragma unroll
  for (int d = 32; d; d >>= 1) {
    sum += __shfl_xor(sum, d, 64);
    sq += __shfl_xor(sq, d, 64);
  }
  if (lane == 0) { red[wave] = sum; red[4 + wave] = sq; }
  __syncthreads();
  sum = red[0] + red[1] + red[2] + red[3];
  sq = red[4] + red[5] + red[6] + red[7];
  float mean = sum * (1.0f / 1024.0f);
  float var = sq * (1.0f / 1024.0f) - mean * mean;
  float rstd = rsqrtf(var + 1e-5f);
#pragma unroll
  for (int t = 0; t < 4; t++) {
    int i = tid + t * 256;
    float o = (h[t] - mean) * rstd * g[i] + be[i];
    of32[base + i] = o;
    if (MODE == 0) obf[base + i] = (bf16)o;
  }
}

// ---------------------------------------------------------------- launch
extern "C" void kernel_launch(void* const* d_in, const int* in_sizes, int n_in, void* d_out,
                              int out_size, void* d_ws, size_t ws_size, hipStream_t stream) {
  const float* x = (const float*)d_in[0];
  const float* ebias = (const float*)d_in[1];
  const unsigned char* pmask = (const unsigned char*)d_in[2];
  const float* wq = (const float*)d_in[3];
  const float* wk = (const float*)d_in[4];
  const float* wv = (const float*)d_in[5];
  const float* wo = (const float*)d_in[6];
  const float* bo = (const float*)d_in[7];
  const float* wg = (const float*)d_in[8];
  const float* bg = (const float*)d_in[9];
  const float* w1 = (const float*)d_in[10];
  const float* b1 = (const float*)d_in[11];
  const float* w2 = (const float*)d_in[12];
  const float* b2 = (const float*)d_in[13];
  const float* ln1g = (const float*)d_in[14];
  const float* ln1b = (const float*)d_in[15];
  const float* ln2g = (const float*)d_in[16];
  const float* ln2b = (const float*)d_in[17];

  char* p = (char*)d_ws;
  bf16* xbf = (bf16*)p;  p += 4194304;
  bf16* wqT = (bf16*)p;  p += 2097152;   // wqT/wkT/wvT/wgT contiguous -> one [4096][1024] B matrix
  bf16* wkT = (bf16*)p;  p += 2097152;
  bf16* wvT = (bf16*)p;  p += 2097152;
  bf16* wgT = (bf16*)p;  p += 2097152;
  bf16* woT = (bf16*)p;  p += 2097152;
  bf16* w1T = (bf16*)p;  p += 4194304;
  bf16* w2T = (bf16*)p;  p += 4194304;
  bf16* qws = (bf16*)p;  p += 4194304;    // [b,h,l,hd]   (QKVG epilogue writes kws/vtws/gws via offsets)
  bf16* kws = (bf16*)p;  p += 4194304;    // [b,h,l,hd]
  bf16* vtws = (bf16*)p; p += 4194304;    // [b,h,hd,l]
  float* gws = (float*)p; p += 8388608;   // sigmoid gate f32
  bf16* ows = (bf16*)p;  p += 4194304;
  float* delta = (float*)p; p += 8388608;
  bf16* x1bf = (bf16*)p; p += 4194304;
  float* x1f = (float*)p; p += 8388608;
  bf16* ffn1 = (bf16*)p; p += 8388608;
  float* ffn2 = (float*)p; p += 8388608;
  size_t base_used = (size_t)(p - (char*)d_ws);
  void* Pws = (void*)p;  // 64MB: f16 scores [b,h,q,k], then bf16 probs in place
  bool fast = (base_used + 67108864ull) <= ws_size;
  (void)kws;

  float* xout = (float*)d_out;
  float* attnf = (float*)d_out + 2097152;  // output 1: [b,q,k,h] f32

  dim3 blk(256);

  // transposes + cast, single launch
  kprep<<<11264, blk, 0, stream>>>(x, xbf, wq, wk, wv, wg, wo, w1, w2, wqT, wkT, wvT, wgT, woT,
                                   w1T, w2T);

  // fused Q|K|V|G projections: M=2048, N=4096, K=1024 (512 blocks -> full GPU)
  gemm_bt<MODE_QKVG, 128><<<dim3(32, 16, 1), blk, 0, stream>>>(
      xbf, wqT, qws, bg, nullptr, 2048, 4096, 1024, 1024, 1024, 0, 0, 1.0f);

  if (fast) {
    // scores f16, coalesced [b,h,q,k]
    gemm_bt<MODE_SCOREF16, 128><<<dim3(8, 8, 32), blk, 0, stream>>>(
        qws, kws, Pws, nullptr, nullptr, 1024, 1024, 64, 64, 64, 65536, 65536, 1.0f);
    attn_softmax16<<<2048, blk, 0, stream>>>(attnf, Pws, ebias, pmask);
    gemm_bt<MODE_PV, 64><<<dim3(1, 8, 32), blk, 0, stream>>>((bf16*)Pws, vtws, ows, nullptr, gws,
                                                             1024, 64, 1024, 1024, 1024, 1048576,
                                                             65536, 1.0f);
  } else {
    gemm_bt<MODE_SCORE_SC, 128><<<dim3(8, 8, 32), blk, 0, stream>>>(
        qws, kws, attnf, nullptr, nullptr, 1024, 1024, 64, 64, 64, 65536, 65536, 1.0f);
    attn_softmax<0><<<4096, blk, 0, stream>>>(attnf, nullptr, ebias, pmask);
    gemm_bt<MODE_PV_SLOW, 64><<<dim3(1, 8, 32), blk, 0, stream>>>(
        attnf, vtws, ows, nullptr, gws, 1024, 64, 1024, 1024, 1024, 0, 65536, 1.0f);
  }

  // delta = o @ wo + bo (BN=64 -> 256 blocks, full machine)
  gemm_bt<MODE_WO, 64><<<dim3(16, 16, 1), blk, 0, stream>>>(ows, woT, delta, bo, nullptr, 2048,
                                                            1024, 1024, 1024, 1024, 0, 0, 1.0f);
  // x1 = LN1(x + delta)
  layernorm_k<0><<<2048, blk, 0, stream>>>(x, delta, ln1g, ln1b, x1f, x1bf);
  // ffn1 = silu(x1 @ w1 + b1)
  gemm_bt<MODE_FFN1, 128><<<dim3(16, 16, 1), blk, 0, stream>>>(x1bf, w1T, ffn1, b1, nullptr, 2048,
                                                               2048, 1024, 1024, 1024, 0, 0, 1.0f);
  // ffn2 = ffn1 @ w2 + b2 (BN=64 -> 256 blocks)
  gemm_bt<MODE_FFN2, 64><<<dim3(16, 16, 1), blk, 0, stream>>>(ffn1, w2T, ffn2, b2, nullptr, 2048,
                                                              1024, 2048, 2048, 2048, 0, 0, 1.0f);
  // out = LN2(x1 + ffn2)
  layernorm_k<1><<<2048, blk, 0, stream>>>(x1f, ffn2, ln2g, ln2b, xout, nullptr);
}

// Round 5
// 491.696 us; speedup vs baseline: 1.3713x; 1.0729x over previous
//
#include <hip/hip_runtime.h>

typedef __bf16 bf16;
typedef _Float16 f16;
typedef bf16 bf16x8 __attribute__((ext_vector_type(8)));
typedef bf16 bf16x4 __attribute__((ext_vector_type(4)));
typedef f16 f16x4 __attribute__((ext_vector_type(4)));
typedef f16 f16x8 __attribute__((ext_vector_type(8)));
typedef float f32x4 __attribute__((ext_vector_type(4)));

// B=2, L=1024, D=1024, H=16, HD=64, FFN=2048, TEMP=8, EPS=1e-5. All I/O f32.

// async global->LDS, 16B per lane. LDS dest = wave-uniform base + lane*16.
__device__ __forceinline__ void gload16(const bf16* g, bf16* l) {
  __builtin_amdgcn_global_load_lds((const __attribute__((address_space(1))) unsigned int*)g,
                                   (__attribute__((address_space(3))) unsigned int*)l, 16, 0, 0);
}

// ---------------------------------------------------------------- prep: 7 transposes + x cast, one kernel
__global__ __launch_bounds__(256) void kprep(
    const float* __restrict__ x, bf16* __restrict__ xbf,
    const float* __restrict__ wq, const float* __restrict__ wk, const float* __restrict__ wv,
    const float* __restrict__ wg, const float* __restrict__ wo, const float* __restrict__ w1,
    const float* __restrict__ w2, bf16* __restrict__ wqT, bf16* __restrict__ wkT,
    bf16* __restrict__ wvT, bf16* __restrict__ wgT, bf16* __restrict__ woT,
    bf16* __restrict__ w1T, bf16* __restrict__ w2T) {
  int bid = blockIdx.x;
  int tid = threadIdx.x;

  if (bid >= 9216) {  // cast segment
    int i = (bid - 9216) * 256 + tid;
    f32x4 v = *(const f32x4*)(x + (long)i * 4);
    bf16x4 o;
#pragma unroll
    for (int j = 0; j < 4; j++) o[j] = (bf16)v[j];
    *(bf16x4*)(xbf + (long)i * 4) = o;
    return;
  }

  __shared__ float t[32][33];
  const float* src;
  bf16* dst;
  int R, C, tile;
  if (bid < 5120) {
    int seg = bid >> 10;
    tile = bid & 1023;
    R = 1024; C = 1024;
    if (seg == 0) { src = wq; dst = wqT; }
    else if (seg == 1) { src = wk; dst = wkT; }
    else if (seg == 2) { src = wv; dst = wvT; }
    else if (seg == 3) { src = wg; dst = wgT; }
    else { src = wo; dst = woT; }
  } else if (bid < 7168) {
    tile = bid - 5120; R = 1024; C = 2048; src = w1; dst = w1T;
  } else {
    tile = bid - 7168; R = 2048; C = 1024; src = w2; dst = w2T;
  }
  int txs = (C == 2048) ? 6 : 5;  // tiles along C
  int c0 = (tile & ((1 << txs) - 1)) << 5, r0 = (tile >> txs) << 5;
  int tx = tid & 31, ty = tid >> 5;
#pragma unroll
  for (int i = 0; i < 32; i += 8)
    t[ty + i][tx] = src[(long)(r0 + ty + i) * C + c0 + tx];
  __syncthreads();
#pragma unroll
  for (int i = 0; i < 32; i += 8)
    dst[(long)(c0 + ty + i) * R + r0 + tx] = (bf16)t[tx][ty + i];
}

// ---------------------------------------------------------------- GEMM (C = A * Bt^T), MFMA bf16
// m97 structure: linear LDS [rows][32] bf16, global_load_lds dwordx4 staging, 2 barriers/iter.
static constexpr int MODE_QK = 0;        // (unused)
static constexpr int MODE_VT = 1;        // (unused)
static constexpr int MODE_SCOREF16 = 3;  // out f16 [b,h,q,k] contiguous (z = b*16+h)
static constexpr int MODE_SCORE_SC = 4;  // out f32 scattered [b,q,k,h] (fallback)
static constexpr int MODE_PV = 5;        // A=Pws bf16 [b,h,q,k]; out bf16 gated
static constexpr int MODE_PV_SLOW = 6;   // A=attn f32 [b,q,k,h] strided; out bf16 gated
static constexpr int MODE_FFN1 = 8;      // out bf16 = silu(acc + bias[n])
static constexpr int MODE_QKVG = 10;     // fused Q|K|V|G projections, N=4096; Out=qws base
static constexpr int MODE_PART = 11;     // split-K partial: f32 raw acc -> Out + z*2^21

template <int MODE, int BN>
__global__ __launch_bounds__(256) void gemm_bt(
    const void* __restrict__ Av, const bf16* __restrict__ Bt, void* __restrict__ Out,
    const float* __restrict__ bias, const float* __restrict__ gate,
    int M, int N, int K, int lda, int ldb, long sA, long sB, float alpha) {
  const int z = blockIdx.z;
  const bf16* A = (const bf16*)Av + (long)z * sA;
  Bt += (long)z * sB;
  const int bb = z >> 4, hh = z & 15;

  constexpr int NT = (BN == 128) ? 4 : 2;
  __shared__ bf16 As[128 * 32];  // linear: global_load_lds needs contiguous lane-order dest
  __shared__ bf16 Bs[BN * 32];

  const int tid = threadIdx.x;
  const int m0 = blockIdx.y * 128, n0 = blockIdx.x * BN;
  const int lane = tid & 63, wave = tid >> 6;
  const int wm = (wave >> 1) * 64;
  const int wn = (BN == 128) ? (wave & 1) * 64 : (wave & 1) * 32;
  const int l15 = lane & 15, quad = lane >> 4;

  // staging geometry: chunk = 16B = 8 bf16
  const int srow = (lane >> 2);          // 0..15 within a wave-instr
  const int skc = (lane & 3) << 3;       // 0,8,16,24

  f32x4 acc[4][NT] = {};

  for (int k0 = 0; k0 < K; k0 += 32) {
    if (MODE == MODE_PV_SLOW) {
      // fallback: strided f32 A gather -> regs; B -> regs; ds_write into linear LDS
      bf16x8 av[2], bv;
#pragma unroll
      for (int u = 0; u < 2; u++) {
        int c = tid + u * 256;
        int row = c >> 2, kc = (c & 3) << 3;
        const float* Af = (const float*)Av;
        long rb = ((long)bb << 24) + hh + ((long)(m0 + row) << 14) + ((long)(k0 + kc) << 4);
#pragma unroll
        for (int j = 0; j < 8; j++) av[u][j] = (bf16)Af[rb + j * 16];
      }
      bv = *(const bf16x8*)(Bt + (long)(n0 + (tid >> 2)) * ldb + (k0 + ((tid & 3) << 3)));
      __syncthreads();
#pragma unroll
      for (int u = 0; u < 2; u++) {
        int c = tid + u * 256;
        *(bf16x8*)&As[c * 8] = av[u];
      }
      *(bf16x8*)&Bs[tid * 8] = bv;
    } else {
      __syncthreads();  // all waves done reading LDS from previous iter
      gload16(A + (long)(m0 + wave * 32 + srow) * lda + (k0 + skc), As + (wave * 2 + 0) * 512);
      gload16(A + (long)(m0 + wave * 32 + 16 + srow) * lda + (k0 + skc),
              As + (wave * 2 + 1) * 512);
      if (BN == 128) {
        gload16(Bt + (long)(n0 + wave * 32 + srow) * ldb + (k0 + skc), Bs + (wave * 2 + 0) * 512);
        gload16(Bt + (long)(n0 + wave * 32 + 16 + srow) * ldb + (k0 + skc),
                Bs + (wave * 2 + 1) * 512);
      } else {
        gload16(Bt + (long)(n0 + wave * 16 + srow) * ldb + (k0 + skc), Bs + wave * 512);
      }
    }
    __syncthreads();  // drains vmcnt (DMA) / lgkmcnt (writes) then barrier

    bf16x8 af[4], bfr[NT];
#pragma unroll
    for (int t = 0; t < 4; t++)
      af[t] = *(const bf16x8*)&As[(wm + t * 16 + l15) * 32 + (quad << 3)];
#pragma unroll
    for (int t = 0; t < NT; t++)
      bfr[t] = *(const bf16x8*)&Bs[(wn + t * 16 + l15) * 32 + (quad << 3)];
#pragma unroll
    for (int mt = 0; mt < 4; mt++)
#pragma unroll
      for (int nt = 0; nt < NT; nt++)
        acc[mt][nt] =
            __builtin_amdgcn_mfma_f32_16x16x32_bf16(af[mt], bfr[nt], acc[mt][nt], 0, 0, 0);
    if (MODE == MODE_PV_SLOW) __syncthreads();
  }

  // C/D layout: col=lane&15, row=quad*4+reg
#pragma unroll
  for (int mt = 0; mt < 4; mt++) {
#pragma unroll
    for (int nt = 0; nt < NT; nt++) {
#pragma unroll
      for (int r = 0; r < 4; r++) {
        int m = m0 + wm + mt * 16 + (quad << 2) + r;
        int n = n0 + wn + nt * 16 + l15;
        float v = acc[mt][nt][r] * alpha;
        if (MODE == MODE_QKVG) {
          int sec = n >> 10, nn = n & 1023;
          bf16* ob = (bf16*)Out;  // qws base; kws/vtws/gws contiguous after it
          if (sec == 0) {
            long off = ((long)((m >> 10) * 16 + (nn >> 6)) * 1024 + (m & 1023)) * 64 + (nn & 63);
            ob[off] = (bf16)(v * 0.125f);
          } else if (sec == 1) {
            long off = ((long)((m >> 10) * 16 + (nn >> 6)) * 1024 + (m & 1023)) * 64 + (nn & 63);
            (ob + 2097152)[off] = (bf16)v;
          } else if (sec == 2) {
            long off = ((long)((m >> 10) * 16 + (nn >> 6)) * 64 + (nn & 63)) * 1024 + (m & 1023);
            (ob + 4194304)[off] = (bf16)v;
          } else {
            float t = v + bias[nn];
            ((float*)(ob + 6291456))[(long)m * 1024 + nn] = 1.0f / (1.0f + __expf(-t));
          }
        } else if (MODE == MODE_SCOREF16) {
          ((f16*)Out)[((long)z << 20) + ((long)m << 10) + n] = (f16)v;
        } else if (MODE == MODE_SCORE_SC) {
          long off = ((long)bb << 24) + ((long)m << 14) + ((long)n << 4) + hh;
          ((float*)Out)[off] = v;
        } else if (MODE == MODE_PV || MODE == MODE_PV_SLOW) {
          long off = ((long)(bb * 1024 + m)) * 1024 + hh * 64 + n;
          ((bf16*)Out)[off] = (bf16)(v * gate[off]);
        } else if (MODE == MODE_FFN1) {
          float t = v + bias[n];
          ((bf16*)Out)[(long)m * N + n] = (bf16)(t / (1.0f + __expf(-t)));
        } else if (MODE == MODE_PART) {
          ((float*)Out)[((long)z << 21) + (long)m * N + n] = v;
        }
      }
    }
  }
}

// ---------------------------------------------------------------- bias + softmax, ALL 16 heads per (b,q)
// 512 threads (8 waves): 33KB LDS -> 4 blocks/CU -> 32 waves/CU (max occupancy).
__global__ __launch_bounds__(512) void attn_softmax16(float* __restrict__ attnf,
                                                      void* __restrict__ Sf,
                                                      const float* __restrict__ ebias,
                                                      const unsigned char* __restrict__ mask) {
  // row stride 1032 f16 = 2064B: 16B-aligned rows, all phases <=2-way banked
  __shared__ f16 sm[16][1032];
  int bx = blockIdx.x;
  int q = bx & 1023, b = bx >> 10;
  int tid = threadIdx.x;
  int lane = tid & 63, wave = tid >> 6;
  long sbase = ((long)b << 24) + ((long)q << 14);  // [b,q,k,h] slice base (floats)

  // ---- phase 1: ebias [k,h] -> LDS f16 [h][k], write-only scatter, mask folded in.
  {
    int h = tid & 15;
    int kb = (tid >> 4) << 4;  // 0..496
#pragma unroll
    for (int it = 0; it < 2; it++) {
      int k0 = kb + it * 512;
      unsigned mw[4];
      *(uint4*)mw = *(const uint4*)(mask + (b << 10) + k0);
      f16 hv[16];
#pragma unroll
      for (int i = 0; i < 16; i++) {
        float v = ebias[sbase + (long)(k0 + i) * 16 + h];
        bool msk = (mw[i >> 2] >> ((i & 3) * 8)) & 255;
        hv[i] = msk ? (f16)(-60000.0f) : (f16)v;
      }
      *(f16x8*)&sm[h][k0] = *(f16x8*)&hv[0];
      *(f16x8*)&sm[h][k0 + 8] = *(f16x8*)&hv[8];
    }
  }

  // prefetch this wave's 2 score rows (global f16, L3-hot) before the barrier
  f16* S = (f16*)Sf;
  f16x8 sv[2][2];
#pragma unroll
  for (int hi = 0; hi < 2; hi++) {
    int h = wave * 2 + hi;
    long srow = (((long)((b << 4) + h) << 10) + q) << 10;
    sv[hi][0] = *(const f16x8*)(S + srow + lane * 8);
    sv[hi][1] = *(const f16x8*)(S + srow + lane * 8 + 512);
  }
  __syncthreads();

  // ---- phase 2: per-wave softmax over 2 heads; P -> Pws (bf16, in-place) + LDS f16
#pragma unroll
  for (int hi = 0; hi < 2; hi++) {
    int h = wave * 2 + hi;
    long srow = (((long)((b << 4) + h) << 10) + q) << 10;
    f16x8 bv0 = *(const f16x8*)&sm[h][lane * 8];
    f16x8 bv1 = *(const f16x8*)&sm[h][lane * 8 + 512];
    float s_[16];
#pragma unroll
    for (int j = 0; j < 8; j++) {
      s_[j] = (float)sv[hi][0][j] + (float)bv0[j];
      s_[8 + j] = (float)sv[hi][1][j] + (float)bv1[j];
    }
    float mx = s_[0];
#pragma unroll
    for (int j = 1; j < 16; j++) mx = fmaxf(mx, s_[j]);
#pragma unroll
    for (int d = 32; d; d >>= 1) mx = fmaxf(mx, __shfl_xor(mx, d, 64));
    float sum = 0.f;
#pragma unroll
    for (int j = 0; j < 16; j++) {
      s_[j] = __expf(s_[j] - mx);
      sum += s_[j];
    }
#pragma unroll
    for (int d = 32; d; d >>= 1) sum += __shfl_xor(sum, d, 64);
    float inv = 1.0f / sum;
    bf16x8 pb0, pb1;
    f16 ph[16];
#pragma unroll
    for (int j = 0; j < 16; j++) {
      float pv = s_[j] * inv;
      ph[j] = (f16)pv;
      if (j < 8) pb0[j] = (bf16)pv; else pb1[j - 8] = (bf16)pv;
    }
    *(bf16x8*)((bf16*)Sf + srow + lane * 8) = pb0;
    *(bf16x8*)((bf16*)Sf + srow + lane * 8 + 512) = pb1;
    *(f16x8*)&sm[h][lane * 8] = *(f16x8*)&ph[0];
    *(f16x8*)&sm[h][lane * 8 + 512] = *(f16x8*)&ph[8];
  }
  __syncthreads();

  // ---- phase 3: attnf f32 [b,q,k,h] transpose-out (coalesced stores; LDS reads word-broadcast)
#pragma unroll
  for (int it = 0; it < 8; it++) {
    int j = tid + it * 512;
    int k = j >> 2, c = (j & 3) << 2;
    f32x4 v;
#pragma unroll
    for (int jj = 0; jj < 4; jj++) v[jj] = (float)sm[c + jj][k];
    *(f32x4*)(attnf + sbase + ((long)k << 4) + c) = v;
  }
}

// ---------------------------------------------------------------- bias + softmax (fallback, f32 scattered)
template <int FAST>
__global__ __launch_bounds__(256) void attn_softmax(float* __restrict__ attnf,
                                                    void* __restrict__ Sf,
                                                    const float* __restrict__ ebias,
                                                    const unsigned char* __restrict__ mask) {
  __shared__ float sm[8][1028];
  int bx = blockIdx.x;
  int hb = (bx & 1) * 8;
  int q = (bx >> 1) & 1023;
  int b = bx >> 11;
  int tid = threadIdx.x;
  int lane = tid & 63, wave = tid >> 6;
  long sbase = ((long)b << 24) + ((long)q << 14) + hb;  // [b,q,k,h] slice base

  for (int i = tid; i < 2048; i += 256) {
    int k = i >> 1, c = (i & 1) * 4;
    long off = sbase + ((long)k << 4) + c;
    f32x4 s = *(const f32x4*)(attnf + off);
    f32x4 e = *(const f32x4*)(ebias + off);
#pragma unroll
    for (int j = 0; j < 4; j++) sm[c + j][k] = s[j] + e[j];
  }
  __syncthreads();

  for (int k = tid; k < 1024; k += 256) {
    if (mask[(b << 10) + k]) {
#pragma unroll
      for (int h = 0; h < 8; h++) sm[h][k] = -1e30f;
    }
  }
  __syncthreads();

  for (int h = wave * 2; h < wave * 2 + 2; h++) {
    float mx = -1e30f;
    for (int k = lane; k < 1024; k += 64) mx = fmaxf(mx, sm[h][k]);
#pragma unroll
    for (int d = 32; d; d >>= 1) mx = fmaxf(mx, __shfl_xor(mx, d, 64));
    float sum = 0.f;
    for (int k = lane; k < 1024; k += 64) {
      float p = __expf(sm[h][k] - mx);
      sm[h][k] = p;
      sum += p;
    }
#pragma unroll
    for (int d = 32; d; d >>= 1) sum += __shfl_xor(sum, d, 64);
    float inv = 1.0f / sum;
    for (int k = lane; k < 1024; k += 64) sm[h][k] *= inv;
  }
  __syncthreads();

  for (int i = tid; i < 2048; i += 256) {
    int k = i >> 1, c = (i & 1) * 4;
    f32x4 v;
#pragma unroll
    for (int j = 0; j < 4; j++) v[j] = sm[c + j][k];
    *(f32x4*)(attnf + sbase + ((long)k << 4) + c) = v;
  }
}

// ---------------------------------------------------------------- layernorm (1024 cols)
// v = a + b + c + colbias[col]; MODE 0 also emits bf16 copy.
template <int MODE>
__global__ __launch_bounds__(256) void layernorm_k(
    const float* __restrict__ a32, const float* __restrict__ b32, const float* __restrict__ c32,
    const float* __restrict__ cb, const float* __restrict__ g, const float* __restrict__ be,
    float* __restrict__ of32, bf16* __restrict__ obf) {
  __shared__ float red[8];
  long base = (long)blockIdx.x << 10;
  int tid = threadIdx.x;
  int lane = tid & 63, wave = tid >> 6;
  float h[4], sum = 0.f, sq = 0.f;
#pragma unroll
  for (int t = 0; t < 4; t++) {
    int i = tid + t * 256;
    float v = a32[base + i] + b32[base + i] + c32[base + i] + cb[i];
    h[t] = v;
    sum += v;
    sq += v * v;
  }
#pragma unroll
  for (int d = 32; d; d >>= 1) {
    sum += __shfl_xor(sum, d, 64);
    sq += __shfl_xor(sq, d, 64);
  }
  if (lane == 0) { red[wave] = sum; red[4 + wave] = sq; }
  __syncthreads();
  sum = red[0] + red[1] + red[2] + red[3];
  sq = red[4] + red[5] + red[6] + red[7];
  float mean = sum * (1.0f / 1024.0f);
  float var = sq * (1.0f / 1024.0f) - mean * mean;
  float rstd = rsqrtf(var + 1e-5f);
#pragma unroll
  for (int t = 0; t < 4; t++) {
    int i = tid + t * 256;
    float o = (h[t] - mean) * rstd * g[i] + be[i];
    of32[base + i] = o;
    if (MODE == 0) obf[base + i] = (bf16)o;
  }
}

// ---------------------------------------------------------------- launch
extern "C" void kernel_launch(void* const* d_in, const int* in_sizes, int n_in, void* d_out,
                              int out_size, void* d_ws, size_t ws_size, hipStream_t stream) {
  const float* x = (const float*)d_in[0];
  const float* ebias = (const float*)d_in[1];
  const unsigned char* pmask = (const unsigned char*)d_in[2];
  const float* wq = (const float*)d_in[3];
  const float* wk = (const float*)d_in[4];
  const float* wv = (const float*)d_in[5];
  const float* wo = (const float*)d_in[6];
  const float* bo = (const float*)d_in[7];
  const float* wg = (const float*)d_in[8];
  const float* bg = (const float*)d_in[9];
  const float* w1 = (const float*)d_in[10];
  const float* b1 = (const float*)d_in[11];
  const float* w2 = (const float*)d_in[12];
  const float* b2 = (const float*)d_in[13];
  const float* ln1g = (const float*)d_in[14];
  const float* ln1b = (const float*)d_in[15];
  const float* ln2g = (const float*)d_in[16];
  const float* ln2b = (const float*)d_in[17];

  char* p = (char*)d_ws;
  bf16* xbf = (bf16*)p;  p += 4194304;
  bf16* wqT = (bf16*)p;  p += 2097152;   // wqT/wkT/wvT/wgT contiguous -> one [4096][1024] B matrix
  bf16* wkT = (bf16*)p;  p += 2097152;
  bf16* wvT = (bf16*)p;  p += 2097152;
  bf16* wgT = (bf16*)p;  p += 2097152;
  bf16* woT = (bf16*)p;  p += 2097152;
  bf16* w1T = (bf16*)p;  p += 4194304;
  bf16* w2T = (bf16*)p;  p += 4194304;
  bf16* qws = (bf16*)p;  p += 4194304;    // [b,h,l,hd]   (QKVG epilogue writes kws/vtws/gws via offsets)
  bf16* kws = (bf16*)p;  p += 4194304;    // [b,h,l,hd]
  bf16* vtws = (bf16*)p; p += 4194304;    // [b,h,hd,l]
  float* gws = (float*)p; p += 8388608;   // sigmoid gate f32
  bf16* ows = (bf16*)p;  p += 4194304;
  float* part = (float*)p; p += 16777216; // split-K partials: delta halves, then ffn2 halves (reused)
  bf16* x1bf = (bf16*)p; p += 4194304;
  float* x1f = (float*)p; p += 8388608;
  bf16* ffn1 = (bf16*)p; p += 8388608;
  size_t base_used = (size_t)(p - (char*)d_ws);
  void* Pws = (void*)p;  // 64MB: f16 scores [b,h,q,k], then bf16 probs in place
  bool fast = (base_used + 67108864ull) <= ws_size;
  (void)kws;

  float* xout = (float*)d_out;
  float* attnf = (float*)d_out + 2097152;  // output 1: [b,q,k,h] f32

  dim3 blk(256);

  // transposes + cast, single launch
  kprep<<<11264, blk, 0, stream>>>(x, xbf, wq, wk, wv, wg, wo, w1, w2, wqT, wkT, wvT, wgT, woT,
                                   w1T, w2T);

  // fused Q|K|V|G projections: M=2048, N=4096, K=1024 (BN=64 -> 1024 blocks, 4/CU)
  gemm_bt<MODE_QKVG, 64><<<dim3(64, 16, 1), blk, 0, stream>>>(
      xbf, wqT, qws, bg, nullptr, 2048, 4096, 1024, 1024, 1024, 0, 0, 1.0f);

  if (fast) {
    // scores f16, coalesced [b,h,q,k]
    gemm_bt<MODE_SCOREF16, 128><<<dim3(8, 8, 32), blk, 0, stream>>>(
        qws, kws, Pws, nullptr, nullptr, 1024, 1024, 64, 64, 64, 65536, 65536, 1.0f);
    attn_softmax16<<<2048, dim3(512), 0, stream>>>(attnf, Pws, ebias, pmask);
    gemm_bt<MODE_PV, 64><<<dim3(1, 8, 32), blk, 0, stream>>>((bf16*)Pws, vtws, ows, nullptr, gws,
                                                             1024, 64, 1024, 1024, 1024, 1048576,
                                                             65536, 1.0f);
  } else {
    gemm_bt<MODE_SCORE_SC, 128><<<dim3(8, 8, 32), blk, 0, stream>>>(
        qws, kws, attnf, nullptr, nullptr, 1024, 1024, 64, 64, 64, 65536, 65536, 1.0f);
    attn_softmax<0><<<4096, blk, 0, stream>>>(attnf, nullptr, ebias, pmask);
    gemm_bt<MODE_PV_SLOW, 64><<<dim3(1, 8, 32), blk, 0, stream>>>(
        attnf, vtws, ows, nullptr, gws, 1024, 64, 1024, 1024, 1024, 0, 65536, 1.0f);
  }

  // delta partials: o @ wo split-K=2 (512 blocks); bo folded into LN1
  gemm_bt<MODE_PART, 64><<<dim3(16, 16, 2), blk, 0, stream>>>(
      ows, woT, part, nullptr, nullptr, 2048, 1024, 512, 1024, 1024, 512, 512, 1.0f);
  // x1 = LN1(x + p0 + p1 + bo)
  layernorm_k<0><<<2048, blk, 0, stream>>>(x, part, part + 2097152, bo, ln1g, ln1b, x1f, x1bf);
  // ffn1 = silu(x1 @ w1 + b1)  (BN=64 -> 512 blocks)
  gemm_bt<MODE_FFN1, 64><<<dim3(32, 16, 1), blk, 0, stream>>>(
      x1bf, w1T, ffn1, b1, nullptr, 2048, 2048, 1024, 1024, 1024, 0, 0, 1.0f);
  // ffn2 partials: ffn1 @ w2 split-K=2 (512 blocks); b2 folded into LN2
  gemm_bt<MODE_PART, 64><<<dim3(16, 16, 2), blk, 0, stream>>>(
      ffn1, w2T, part, nullptr, nullptr, 2048, 1024, 1024, 2048, 2048, 1024, 1024, 1.0f);
  // out = LN2(x1 + f0 + f1 + b2)
  layernorm_k<1><<<2048, blk, 0, stream>>>(x1f, part, part + 2097152, b2, ln2g, ln2b, xout,
                                           nullptr);
}